// Round 14
// baseline (523.520 us; speedup 1.0000x reference)
//
#include <hip/hip_runtime.h>
#include <math.h>

#define N_NODES 10000
#define D_IN    512
#define D_H     256
#define NCLS    40
#define NEDGE   160000
#define KTOP    16
#define NFRAG   625            // 10000 / 16 column fragments
#define CSPL    13             // column splits
#define ROWS    128            // rows per block (16 per wave, 8 waves)
#define RT      79             // ceil(10000/128) row tiles -> grid 79*13 = 1027 ~ 1024 concurrent
#define SLOTS   6              // per-lane-stream top-6
#define LSTREAM 52             // lane-streams per row = CSPL * 4 lh-groups
#define CPR     (LSTREAM * SLOTS)   // candidates per row = 312
#define RESC    32             // exactly-rescored candidates per row

typedef __attribute__((ext_vector_type(8))) short bf16x8;
typedef __attribute__((ext_vector_type(4))) float f32x4;

__device__ __forceinline__ void gload_lds16(const void* g, void* l) {
    __builtin_amdgcn_global_load_lds(
        (const __attribute__((address_space(1))) void*)g,
        (__attribute__((address_space(3))) void*)l, 16, 0, 0);
}

// ---------------- transpose weights ----------------
__global__ void transpose_kernel(const float* __restrict__ W1_l, const float* __restrict__ W1_r,
                                 const float* __restrict__ W2_l, const float* __restrict__ W2_r,
                                 float* __restrict__ W1lT, float* __restrict__ W1rT,
                                 float* __restrict__ W2lT, float* __restrict__ W2rT) {
    int i = blockIdx.x * 256 + threadIdx.x;
    if (i < D_H * D_IN) {
        int r = i / D_IN, c = i % D_IN;
        W1lT[(size_t)c * D_H + r] = W1_l[i];
        W1rT[(size_t)c * D_H + r] = W1_r[i];
    }
    if (i < NCLS * D_H) {
        int r = i / D_H, c = i % D_H;
        W2lT[(size_t)c * NCLS + r] = W2_l[i];
        W2rT[(size_t)c * NCLS + r] = W2_r[i];
    }
}

// ---------------- degree count (int) ----------------
__global__ void count_kernel(const int* __restrict__ dst, int* __restrict__ cnt) {
    int e = blockIdx.x * 256 + threadIdx.x;
    if (e < NEDGE) {
        int d = dst[e];
        d = (d >= 0 && d < N_NODES) ? d : 0;
        atomicAdd(&cnt[d], 1);
    }
}

// ---------------- prefix scan -> rowptr, cursor ----------------
__global__ void prefix_kernel(const int* __restrict__ cnt, int* __restrict__ rowptr,
                              int* __restrict__ cursor) {
    __shared__ int sp[256];
    int t = threadIdx.x;
    int b0 = t * 40;
    int e0 = (b0 + 40 < N_NODES) ? b0 + 40 : N_NODES;
    int s = 0;
    for (int i = b0; i < e0; i++) s += cnt[i];
    sp[t] = s;
    __syncthreads();
    for (int o = 1; o < 256; o <<= 1) {
        int add = (t >= o) ? sp[t - o] : 0;
        __syncthreads();
        sp[t] += add;
        __syncthreads();
    }
    int run = sp[t] - s;     // exclusive prefix
    for (int i = b0; i < e0; i++) {
        rowptr[i] = run; cursor[i] = run; run += cnt[i];
    }
    if (t == 255) rowptr[N_NODES] = run;
}

// ---------------- bucket edges by dst ----------------
__global__ void bucket_kernel(const int* __restrict__ src, const int* __restrict__ dst,
                              int* __restrict__ cursor, int* __restrict__ nbr) {
    int e = blockIdx.x * 256 + threadIdx.x;
    if (e < NEDGE) {
        int d = dst[e];
        d = (d >= 0 && d < N_NODES) ? d : 0;
        int p = atomicAdd(&cursor[d], 1);
        if (p >= 0 && p < NEDGE) {
            int s = src[e];
            nbr[p] = (s >= 0 && s < N_NODES) ? s : 0;
        }
    }
}

// ---------------- xw1 = x @ W1_l^T ; xwr = x @ W1_r^T ----------------
__global__ __launch_bounds__(256) void proj1_kernel(const float* __restrict__ x,
        const float* __restrict__ W1lT, const float* __restrict__ W1rT,
        float* __restrict__ xw1, float* __restrict__ xwr) {
    __shared__ float sx[8][D_IN];
    int tid = threadIdx.x;
    int nb0 = blockIdx.x * 8;
    #pragma unroll
    for (int u = 0; u < 4; u++) {
        int s = tid + u * 256;          // 0..1023
        int nb = s >> 7;                // 0..7
        int c4 = (s & 127) << 2;        // 0..508
        int n = nb0 + nb;
        float4 v = make_float4(0.f, 0.f, 0.f, 0.f);
        if (n < N_NODES) v = *(const float4*)&x[(size_t)n * D_IN + c4];
        *(float4*)&sx[nb][c4] = v;
    }
    __syncthreads();
    int j = tid;
    float accl[8] = {0,0,0,0,0,0,0,0};
    float accr[8] = {0,0,0,0,0,0,0,0};
    for (int i = 0; i < D_IN; i += 4) {
        float wl0 = W1lT[(size_t)(i + 0) * D_H + j];
        float wl1 = W1lT[(size_t)(i + 1) * D_H + j];
        float wl2 = W1lT[(size_t)(i + 2) * D_H + j];
        float wl3 = W1lT[(size_t)(i + 3) * D_H + j];
        float wr0 = W1rT[(size_t)(i + 0) * D_H + j];
        float wr1 = W1rT[(size_t)(i + 1) * D_H + j];
        float wr2 = W1rT[(size_t)(i + 2) * D_H + j];
        float wr3 = W1rT[(size_t)(i + 3) * D_H + j];
        #pragma unroll
        for (int nb = 0; nb < 8; nb++) {
            float4 xx = *(const float4*)&sx[nb][i];
            float tl = accl[nb], tr = accr[nb];
            tl = fmaf(xx.x, wl0, tl); tl = fmaf(xx.y, wl1, tl);
            tl = fmaf(xx.z, wl2, tl); tl = fmaf(xx.w, wl3, tl);
            tr = fmaf(xx.x, wr0, tr); tr = fmaf(xx.y, wr1, tr);
            tr = fmaf(xx.z, wr2, tr); tr = fmaf(xx.w, wr3, tr);
            accl[nb] = tl; accr[nb] = tr;
        }
    }
    for (int nb = 0; nb < 8; nb++) {
        int n = nb0 + nb;
        if (n < N_NODES) {
            xw1[(size_t)n * D_H + j] = accl[nb];
            xwr[(size_t)n * D_H + j] = accr[nb];
        }
    }
}

// ---------------- fused: h = elu(mean(xw1[nbr]) + b1 + xwr); en/enb = normalize(h);
//                  out_h = h; hwl = h @ W2_l^T; hwr = h @ W2_r^T ----------------
__global__ __launch_bounds__(256) void gather_h_fused_kernel(const float* __restrict__ xw1,
        const float* __restrict__ xwr, const int* __restrict__ nbr,
        const int* __restrict__ rowptr, const int* __restrict__ cnt,
        const float* __restrict__ b1, const float* __restrict__ W2lT,
        const float* __restrict__ W2rT, float* __restrict__ h, float* __restrict__ en,
        unsigned short* __restrict__ enb, float* __restrict__ outh,
        float* __restrict__ hwl, float* __restrict__ hwr) {
    __shared__ float sh[4][D_H];
    int wid = threadIdx.x >> 6, lane = threadIdx.x & 63;
    int n = blockIdx.x * 4 + wid;
    if (n >= N_NODES) return;
    int st = rowptr[n], deg = cnt[n];
    float a[4] = {0,0,0,0};
    for (int j = 0; j < deg; j++) {
        int s = nbr[st + j];
        float4 v = *(const float4*)&xw1[(size_t)s * D_H + lane * 4];
        a[0] += v.x; a[1] += v.y; a[2] += v.z; a[3] += v.w;
    }
    float inv = 1.0f / fmaxf((float)deg, 1.0f);
    float4 r4 = *(const float4*)&xwr[(size_t)n * D_H + lane * 4];
    float4 bb = *(const float4*)&b1[lane * 4];
    float o0 = a[0] * inv + bb.x + r4.x;
    float o1 = a[1] * inv + bb.y + r4.y;
    float o2 = a[2] * inv + bb.z + r4.z;
    float o3 = a[3] * inv + bb.w + r4.w;
    o0 = o0 > 0.f ? o0 : expm1f(o0);
    o1 = o1 > 0.f ? o1 : expm1f(o1);
    o2 = o2 > 0.f ? o2 : expm1f(o2);
    o3 = o3 > 0.f ? o3 : expm1f(o3);
    float4 hv = make_float4(o0, o1, o2, o3);
    *(float4*)&h[(size_t)n * D_H + lane * 4] = hv;
    *(float4*)&outh[(size_t)n * D_H + lane * 4] = hv;
    *(float4*)&sh[wid][lane * 4] = hv;          // wave-private row; no block sync needed

    // norm -> en (fp32) + enb (bf16)
    float ss = o0 * o0 + o1 * o1 + o2 * o2 + o3 * o3;
    for (int o = 32; o; o >>= 1) ss += __shfl_xor(ss, o);
    float ninv = 1.0f / fmaxf(sqrtf(ss), 1e-8f);
    float e[4] = {o0 * ninv, o1 * ninv, o2 * ninv, o3 * ninv};
    *(float4*)&en[(size_t)n * D_H + lane * 4] = make_float4(e[0], e[1], e[2], e[3]);
    unsigned int p[4];
    #pragma unroll
    for (int k = 0; k < 4; k++) {
        unsigned int ub = __float_as_uint(e[k]);
        p[k] = (ub + 0x7FFFu + ((ub >> 16) & 1u)) >> 16;   // RNE to bf16
    }
    uint2 packed = make_uint2(p[0] | (p[1] << 16), p[2] | (p[3] << 16));
    *(uint2*)&enb[(size_t)n * D_H + lane * 4] = packed;

    // proj2: hwl/hwr for own node (lanes 0..39)
    if (lane < NCLS) {
        float al = 0.f, ar = 0.f;
        for (int i = 0; i < D_H; i++) {
            float hvv = sh[wid][i];
            al = fmaf(hvv, W2lT[(size_t)i * NCLS + lane], al);
            ar = fmaf(hvv, W2rT[(size_t)i * NCLS + lane], ar);
        }
        hwl[(size_t)n * NCLS + lane] = al;
        hwr[(size_t)n * NCLS + lane] = ar;
    }
}

// ---------------- lcls = log_softmax(elu(mean(hwl[nbr]) + b2 + hwr)) ----------------
__global__ void gather_lc_kernel(const float* __restrict__ hwl, const float* __restrict__ hwr,
                                 const int* __restrict__ nbr, const int* __restrict__ rowptr,
                                 const int* __restrict__ cnt, const float* __restrict__ b2,
                                 float* __restrict__ lcls) {
    int wid = threadIdx.x >> 6, lane = threadIdx.x & 63;
    int n = blockIdx.x * 4 + wid;
    if (n >= N_NODES) return;
    int st = rowptr[n], deg = cnt[n];
    float a = 0.f;
    if (lane < NCLS) {
        for (int j = 0; j < deg; j++) {
            int s = nbr[st + j];
            a += hwl[(size_t)s * NCLS + lane];
        }
    }
    float inv = 1.0f / fmaxf((float)deg, 1.0f);
    float v;
    if (lane < NCLS) {
        v = a * inv + b2[lane] + hwr[(size_t)n * NCLS + lane];
        v = v > 0.f ? v : expm1f(v);
    } else {
        v = -INFINITY;
    }
    float m = v;
    for (int o = 32; o; o >>= 1) m = fmaxf(m, __shfl_xor(m, o));
    float ex = (lane < NCLS) ? expf(v - m) : 0.0f;
    float s = ex;
    for (int o = 32; o; o >>= 1) s += __shfl_xor(s, o);
    if (lane < NCLS) lcls[(size_t)n * NCLS + lane] = v - m - logf(s);
}

// ---------------- MFMA bf16 prefilter, 128 rows/block, ring-3 + counted vmcnt ----------------
// 8 waves process the SAME fragment; wave w owns rows rt*128 + w*16 + (l&15).
// A-tile (8KB) staged via ONE global_load_lds per wave (lane-contiguous 1KB, wave-uniform
// base; pre-swizzled global src) into a 3-buffer ring. Per iteration:
//   [A] counted s_waitcnt (tile f landed; tiles f+1/f+2 stay in flight)
//   [B] raw s_barrier + sched_barrier
//   [C] issue tile f+2 + mask f+2
//   [D] compute tile f
// Per-iteration VMEM group = {1 gload_lds, 1 mask load} = 2 ops -> vmcnt(2) mid-loop
// (safe under any intra-group order); vmcnt(0) peeled for first/last iterations.
// pv/pi bit-identical to R12/R13 (same stream partition, same value order).
__global__ __launch_bounds__(512) void sim_topk_kernel(const unsigned short* __restrict__ enb,
        const float* __restrict__ mask, float* __restrict__ pv, int* __restrict__ pi) {
    __shared__ __align__(16) char Abuf[3][8192];   // 3 x 8KB ring

    int rt = blockIdx.x / CSPL, cs = blockIdx.x % CSPL;
    int tid = threadIdx.x;
    int w = tid >> 6, l = tid & 63;
    int l15 = l & 15, lh = l >> 4;            // lh: 0..3
    int r = rt * ROWS + w * 16 + l15;         // this lane's sim row
    int rc = (r < N_NODES) ? r : (N_NODES - 1);

    // contiguous fragment chunk: cs=0 -> [0,49), cs>=1 -> [48cs+1, 48cs+49)
    int fbeg = cs * 48 + (cs ? 1 : 0);
    int fend = fbeg + (cs ? 48 : 49);

    // B fragments: own row of enb, full K=256
    bf16x8 bfr[8];
    const unsigned short* brow = enb + (size_t)rc * D_H + 8 * lh;
    #pragma unroll
    for (int ks = 0; ks < 8; ks++) bfr[ks] = *(const bf16x8*)(brow + ks * 32);

    float tv[SLOTS]; int ti[SLOTS];
    #pragma unroll
    for (int k = 0; k < SLOTS; k++) { tv[k] = -INFINITY; ti[k] = 0; }

    const float* mrow = mask + (size_t)rc * N_NODES;

    // swizzled ds_read byte offsets within a tile (8, per-lane constants)
    int offs[8];
    {
        int swz = (l15 & 7) << 4;
        #pragma unroll
        for (int ks = 0; ks < 8; ks++) offs[ks] = (lh * 16 + ks * 64) ^ swz;
    }

    // staging geometry: wave w stages tile bytes [w*1024, w*1024+1024) with ONE gload_lds.
    // linear LDS slot tid*16 -> tile row = tid>>5, 16B-granule tcol = tid&31,
    // pre-swizzled source granule g = tcol ^ (row&7).
    int srow = tid >> 5;                       // 0..15
    int g    = (tid & 31) ^ (srow & 7);
    const char* gB = (const char*)enb;
    char* lds0 = &Abuf[0][0];
    char* ldsw = lds0 + w * 1024;              // wave-uniform base

    // prologue: stage fbeg -> buf0, fbeg+1 -> buf1 (chunk length >= 48 so fbeg+1 < fend)
    gload_lds16(gB + (((size_t)(fbeg * 16 + srow)) << 9) + g * 16, ldsw);
    gload_lds16(gB + (((size_t)((fbeg + 1) * 16 + srow)) << 9) + g * 16, ldsw + 8192);

    float4 mm  = *(const float4*)&mrow[fbeg * 16 + lh * 4];
    float4 mm1 = *(const float4*)&mrow[(fbeg + 1) * 16 + lh * 4];

    int cur = 0;
    for (int f = fbeg; f < fend; ++f) {
        // [A] tile-f loads complete (counted mid-loop; full drain on first/last iteration)
        if (f == fbeg || f + 1 >= fend) asm volatile("s_waitcnt vmcnt(0)" ::: "memory");
        else                            asm volatile("s_waitcnt vmcnt(2)" ::: "memory");
        // [B] all waves' tile-f loads landed; all waves done reading the ring slot being reused
        __builtin_amdgcn_s_barrier();
        __builtin_amdgcn_sched_barrier(0);
        // [C] issue tile f+2 into the freed buffer; prefetch mask f+2
        float4 mm2 = make_float4(0.f, 0.f, 0.f, 0.f);
        if (f + 2 < fend) {
            int nb = cur + 2; nb = (nb >= 3) ? nb - 3 : nb;
            gload_lds16(gB + (((size_t)((f + 2) * 16 + srow)) << 9) + g * 16, ldsw + nb * 8192);
            mm2 = *(const float4*)&mrow[(f + 2) * 16 + lh * 4];
        }
        // [D] compute on buf[cur]
        const char* lbase = lds0 + cur * 8192 + l15 * 512;
        f32x4 acc = {0.f, 0.f, 0.f, 0.f};
        #pragma unroll
        for (int ks = 0; ks < 8; ks++) {
            bf16x8 af = *(const bf16x8*)(lbase + offs[ks]);
            acc = __builtin_amdgcn_mfma_f32_16x16x32_bf16(af, bfr[ks], acc, 0, 0, 0);
        }

        int c0 = f * 16 + lh * 4;
        float vv[4];
        vv[0] = acc[0] * mm.x; vv[1] = acc[1] * mm.y;
        vv[2] = acc[2] * mm.z; vv[3] = acc[3] * mm.w;
        // branchless top-6 insert, shared compares; strict > keeps earliest col on ties
        #pragma unroll
        for (int j = 0; j < 4; j++) {
            float v = vv[j]; int c = c0 + j;
            bool hh[SLOTS];
            #pragma unroll
            for (int k = 0; k < SLOTS; k++) hh[k] = tv[k] < v;
            float nv[SLOTS]; int ni[SLOTS];
            #pragma unroll
            for (int k = 0; k < SLOTS - 1; k++) {
                nv[k] = hh[k + 1] ? tv[k + 1] : (hh[k] ? v : tv[k]);
                ni[k] = hh[k + 1] ? ti[k + 1] : (hh[k] ? c : ti[k]);
            }
            nv[SLOTS - 1] = hh[SLOTS - 1] ? v : tv[SLOTS - 1];
            ni[SLOTS - 1] = hh[SLOTS - 1] ? c : ti[SLOTS - 1];
            #pragma unroll
            for (int k = 0; k < SLOTS; k++) { tv[k] = nv[k]; ti[k] = ni[k]; }
        }

        mm = mm1; mm1 = mm2;
        cur = (cur == 2) ? 0 : cur + 1;
    }

    if (r < N_NODES) {
        int stream = cs * 4 + lh;              // 0..51 lane-stream id
        float* pvp = pv + (size_t)r * CPR + stream;
        int*   pip = pi + (size_t)r * CPR + stream;
        #pragma unroll
        for (int k = 0; k < SLOTS; k++) { pvp[k * LSTREAM] = tv[k]; pip[k * LSTREAM] = ti[k]; }
    }
}

// ---------------- top-32 by bf16 value -> exact fp32 rescore -> top-16 -> fusion -> blend ----------------
__global__ __launch_bounds__(256) void rescore_merge_kernel(const float* __restrict__ en,
        const float* __restrict__ mask, const float* __restrict__ pv, const int* __restrict__ pi,
        const int* __restrict__ y, const float* __restrict__ lcls, float* __restrict__ out) {
    __shared__ float sen[4][D_H];
    int wid = threadIdx.x >> 6, lane = threadIdx.x & 63;
    int r = blockIdx.x * 4 + wid;
    if (r >= N_NODES) return;
    *(float4*)&sen[wid][lane * 4] = *(const float4*)&en[(size_t)r * D_H + lane * 4];

    // ---- Phase A: lanes 0..51 own stream `lane` (6 ascending slots); pick row top-32 ----
    float v0 = -INFINITY, v1 = -INFINITY, v2 = -INFINITY;
    float v3 = -INFINITY, v4 = -INFINITY, v5 = -INFINITY;
    int   i0 = 0x7FFFFFFF, i1 = 0x7FFFFFFF, i2 = 0x7FFFFFFF;
    int   i3 = 0x7FFFFFFF, i4 = 0x7FFFFFFF, i5 = 0x7FFFFFFF;
    if (lane < LSTREAM) {
        const float* pvr = pv + (size_t)r * CPR + lane;
        const int*   pir = pi + (size_t)r * CPR + lane;
        v0 = pvr[0*LSTREAM]; v1 = pvr[1*LSTREAM]; v2 = pvr[2*LSTREAM];
        v3 = pvr[3*LSTREAM]; v4 = pvr[4*LSTREAM]; v5 = pvr[5*LSTREAM];
        i0 = pir[0*LSTREAM]; i1 = pir[1*LSTREAM]; i2 = pir[2*LSTREAM];
        i3 = pir[3*LSTREAM]; i4 = pir[4*LSTREAM]; i5 = pir[5*LSTREAM];
    }
    int p = SLOTS - 1;              // pointer to current lane max (slots ascending)
    int my_cand = 0;
    #pragma unroll 1
    for (int t = 0; t < RESC; t++) {
        float cur  = (p < 0) ? -INFINITY :
                     (p == 5 ? v5 : p == 4 ? v4 : p == 3 ? v3 : p == 2 ? v2 : p == 1 ? v1 : v0);
        int   curi = (p < 0) ? 0x7FFFFFFF :
                     (p == 5 ? i5 : p == 4 ? i4 : p == 3 ? i3 : p == 2 ? i2 : p == 1 ? i1 : i0);
        float rv = cur; int ri = curi;
        #pragma unroll
        for (int o = 1; o < 64; o <<= 1) {
            float ov = __shfl_xor(rv, o); int oi = __shfl_xor(ri, o);
            bool bet = (ov > rv) || (ov == rv && oi < ri);
            rv = bet ? ov : rv; ri = bet ? oi : ri;
        }
        if (curi == ri && p >= 0) p--;      // indices unique per row -> only winner decrements
        if (lane == t) my_cand = ri;
    }
    // broadcast: lane L and L+32 rescore candidate sel[L&31]
    int cand = __shfl(my_cand, lane & 31);
    cand = (cand >= 0 && cand < N_NODES) ? cand : 0;

    __syncthreads();   // sen ready

    // ---- Phase B: exact fp32 dot, 2 lanes per candidate (k-halves) ----
    int half = lane >> 5;               // 0 or 1
    const float* erow = &en[(size_t)cand * D_H + half * 128];
    const float* srow = &sen[wid][half * 128];
    float dot = 0.0f;
    #pragma unroll 8
    for (int k = 0; k < 128; k += 4) {
        float4 e = *(const float4*)&erow[k];
        dot = fmaf(srow[k + 0], e.x, dot);
        dot = fmaf(srow[k + 1], e.y, dot);
        dot = fmaf(srow[k + 2], e.z, dot);
        dot = fmaf(srow[k + 3], e.w, dot);
    }
    dot += __shfl_xor(dot, 32);
    float cv = (lane < RESC) ? dot * mask[(size_t)r * N_NODES + cand] : -INFINITY;

    // ---- Phase C: exact top-16 -> label fusion -> log-softmax -> blend ----
    float fc = 0.0f;
    #pragma unroll 1
    for (int t = 0; t < KTOP; t++) {
        float rv = cv; int ri = (lane < RESC) ? cand : 0x7FFFFFFF;
        #pragma unroll
        for (int o = 1; o < 64; o <<= 1) {
            float ov = __shfl_xor(rv, o); int oi = __shfl_xor(ri, o);
            bool bet = (ov > rv) || (ov == rv && oi < ri);
            rv = bet ? ov : rv; ri = bet ? oi : ri;
        }
        if (lane < RESC && cand == ri) cv = -INFINITY;
        int ris = (ri >= 0 && ri < N_NODES) ? ri : 0;
        int lbl = y[ris];
        if (lane == lbl) fc += expf(rv);
    }
    float fval = (lane < NCLS) ? fc : -INFINITY;
    float m = fval;
    for (int o = 32; o; o >>= 1) m = fmaxf(m, __shfl_xor(m, o));
    float ex = (lane < NCLS) ? expf(fval - m) : 0.0f;
    float s = ex;
    for (int o = 32; o; o >>= 1) s += __shfl_xor(s, o);
    if (lane < NCLS)
        out[(size_t)r * NCLS + lane] = 0.5f * lcls[(size_t)r * NCLS + lane]
                                     + 0.5f * (fval - m - logf(s));
}

extern "C" void kernel_launch(void* const* d_in, const int* in_sizes, int n_in,
                              void* d_out, int out_size, void* d_ws, size_t ws_size,
                              hipStream_t stream) {
    const float* x    = (const float*)d_in[0];
    const int*   ei   = (const int*)  d_in[1];
    const int*   y    = (const int*)  d_in[2];
    const float* mask = (const float*)d_in[3];
    const float* W1_l = (const float*)d_in[4];
    const float* b1   = (const float*)d_in[5];
    const float* W1_r = (const float*)d_in[6];
    const float* W2_l = (const float*)d_in[7];
    const float* b2   = (const float*)d_in[8];
    const float* W2_r = (const float*)d_in[9];

    float* out   = (float*)d_out;
    float* out_h = out + (size_t)N_NODES * NCLS;

    int*   cnt    = (int*)d_ws;                       // 10240
    int*   rowptr = cnt + 10240;                      // 10304
    int*   cursor = rowptr + 10304;                   // 10240
    int*   nbr    = cursor + 10240;                   // 160256
    float* xw1    = (float*)(nbr + 160256);           // N*256
    float* xwr    = xw1 + (size_t)N_NODES * D_H;      // N*256
    float* h      = xwr + (size_t)N_NODES * D_H;      // N*256
    float* en     = h   + (size_t)N_NODES * D_H;      // N*256
    unsigned short* enb = (unsigned short*)(en + (size_t)N_NODES * D_H);  // N*256 bf16
    float* lcls   = (float*)(enb + (size_t)N_NODES * D_H);                // N*40
    float* hwl    = lcls + (size_t)N_NODES * NCLS;    // N*40
    float* hwr    = hwl + (size_t)N_NODES * NCLS;     // N*40
    float* W1lT   = hwr + (size_t)N_NODES * NCLS;
    float* W1rT   = W1lT + (size_t)D_IN * D_H;
    float* W2lT   = W1rT + (size_t)D_IN * D_H;
    float* W2rT   = W2lT + (size_t)D_H * NCLS;
    // pv aliases xw1+xwr (N*512 floats, dead after gather_h_fused which runs before sim_topk)
    float* pv     = xw1;                                 // N*312 used
    int*   pi     = (int*)(W2rT + (size_t)D_H * NCLS);   // N*312 used

    const int* src = ei;
    const int* dst = ei + NEDGE;

    hipMemsetAsync(cnt, 0, 10240 * sizeof(int), stream);

    transpose_kernel<<<(D_H * D_IN + 255) / 256, 256, 0, stream>>>(
        W1_l, W1_r, W2_l, W2_r, W1lT, W1rT, W2lT, W2rT);
    count_kernel<<<(NEDGE + 255) / 256, 256, 0, stream>>>(dst, cnt);
    prefix_kernel<<<1, 256, 0, stream>>>(cnt, rowptr, cursor);
    bucket_kernel<<<(NEDGE + 255) / 256, 256, 0, stream>>>(src, dst, cursor, nbr);
    proj1_kernel<<<(N_NODES + 7) / 8, 256, 0, stream>>>(x, W1lT, W1rT, xw1, xwr);
    gather_h_fused_kernel<<<(N_NODES + 3) / 4, 256, 0, stream>>>(
        xw1, xwr, nbr, rowptr, cnt, b1, W2lT, W2rT, h, en, enb, out_h, hwl, hwr);
    gather_lc_kernel<<<(N_NODES + 3) / 4, 256, 0, stream>>>(hwl, hwr, nbr, rowptr, cnt, b2, lcls);
    sim_topk_kernel<<<RT * CSPL, 512, 0, stream>>>(enb, mask, pv, pi);
    rescore_merge_kernel<<<(N_NODES + 3) / 4, 256, 0, stream>>>(en, mask, pv, pi, y, lcls, out);
}

// Round 15
// 492.321 us; speedup vs baseline: 1.0634x; 1.0634x over previous
//
#include <hip/hip_runtime.h>
#include <math.h>

#define N_NODES 10000
#define D_IN    512
#define D_H     256
#define NCLS    40
#define NEDGE   160000
#define KTOP    16
#define NFRAG   625            // 10000 / 16 column fragments
#define CSPL    13             // column splits
#define ROWS    64             // rows per block (16 per wave)
#define RT      157            // ceil(10000/64) row tiles
#define SLOTS   6              // per-lane-stream top-6
#define LSTREAM 52             // lane-streams per row = CSPL * 4 lh-groups
#define CPR     (LSTREAM * SLOTS)   // candidates per row = 312
#define RESC    32             // exactly-rescored candidates per row

typedef __attribute__((ext_vector_type(8))) short bf16x8;
typedef __attribute__((ext_vector_type(4))) float f32x4;

__device__ __forceinline__ void gload_lds16(const void* g, void* l) {
    __builtin_amdgcn_global_load_lds(
        (const __attribute__((address_space(1))) void*)g,
        (__attribute__((address_space(3))) void*)l, 16, 0, 0);
}

// ---------------- transpose weights ----------------
__global__ void transpose_kernel(const float* __restrict__ W1_l, const float* __restrict__ W1_r,
                                 const float* __restrict__ W2_l, const float* __restrict__ W2_r,
                                 float* __restrict__ W1lT, float* __restrict__ W1rT,
                                 float* __restrict__ W2lT, float* __restrict__ W2rT) {
    int i = blockIdx.x * 256 + threadIdx.x;
    if (i < D_H * D_IN) {
        int r = i / D_IN, c = i % D_IN;
        W1lT[(size_t)c * D_H + r] = W1_l[i];
        W1rT[(size_t)c * D_H + r] = W1_r[i];
    }
    if (i < NCLS * D_H) {
        int r = i / D_H, c = i % D_H;
        W2lT[(size_t)c * NCLS + r] = W2_l[i];
        W2rT[(size_t)c * NCLS + r] = W2_r[i];
    }
}

// ---------------- degree count (int) ----------------
__global__ void count_kernel(const int* __restrict__ dst, int* __restrict__ cnt) {
    int e = blockIdx.x * 256 + threadIdx.x;
    if (e < NEDGE) {
        int d = dst[e];
        d = (d >= 0 && d < N_NODES) ? d : 0;
        atomicAdd(&cnt[d], 1);
    }
}

// ---------------- prefix scan -> rowptr, cursor ----------------
__global__ void prefix_kernel(const int* __restrict__ cnt, int* __restrict__ rowptr,
                              int* __restrict__ cursor) {
    __shared__ int sp[256];
    int t = threadIdx.x;
    int b0 = t * 40;
    int e0 = (b0 + 40 < N_NODES) ? b0 + 40 : N_NODES;
    int s = 0;
    for (int i = b0; i < e0; i++) s += cnt[i];
    sp[t] = s;
    __syncthreads();
    for (int o = 1; o < 256; o <<= 1) {
        int add = (t >= o) ? sp[t - o] : 0;
        __syncthreads();
        sp[t] += add;
        __syncthreads();
    }
    int run = sp[t] - s;     // exclusive prefix
    for (int i = b0; i < e0; i++) {
        rowptr[i] = run; cursor[i] = run; run += cnt[i];
    }
    if (t == 255) rowptr[N_NODES] = run;
}

// ---------------- bucket edges by dst ----------------
__global__ void bucket_kernel(const int* __restrict__ src, const int* __restrict__ dst,
                              int* __restrict__ cursor, int* __restrict__ nbr) {
    int e = blockIdx.x * 256 + threadIdx.x;
    if (e < NEDGE) {
        int d = dst[e];
        d = (d >= 0 && d < N_NODES) ? d : 0;
        int p = atomicAdd(&cursor[d], 1);
        if (p >= 0 && p < NEDGE) {
            int s = src[e];
            nbr[p] = (s >= 0 && s < N_NODES) ? s : 0;
        }
    }
}

// ---------------- xw1 = x @ W1_l^T ; xwr = x @ W1_r^T ----------------
__global__ __launch_bounds__(256) void proj1_kernel(const float* __restrict__ x,
        const float* __restrict__ W1lT, const float* __restrict__ W1rT,
        float* __restrict__ xw1, float* __restrict__ xwr) {
    __shared__ float sx[8][D_IN];
    int tid = threadIdx.x;
    int nb0 = blockIdx.x * 8;
    #pragma unroll
    for (int u = 0; u < 4; u++) {
        int s = tid + u * 256;          // 0..1023
        int nb = s >> 7;                // 0..7
        int c4 = (s & 127) << 2;        // 0..508
        int n = nb0 + nb;
        float4 v = make_float4(0.f, 0.f, 0.f, 0.f);
        if (n < N_NODES) v = *(const float4*)&x[(size_t)n * D_IN + c4];
        *(float4*)&sx[nb][c4] = v;
    }
    __syncthreads();
    int j = tid;
    float accl[8] = {0,0,0,0,0,0,0,0};
    float accr[8] = {0,0,0,0,0,0,0,0};
    for (int i = 0; i < D_IN; i += 4) {
        float wl0 = W1lT[(size_t)(i + 0) * D_H + j];
        float wl1 = W1lT[(size_t)(i + 1) * D_H + j];
        float wl2 = W1lT[(size_t)(i + 2) * D_H + j];
        float wl3 = W1lT[(size_t)(i + 3) * D_H + j];
        float wr0 = W1rT[(size_t)(i + 0) * D_H + j];
        float wr1 = W1rT[(size_t)(i + 1) * D_H + j];
        float wr2 = W1rT[(size_t)(i + 2) * D_H + j];
        float wr3 = W1rT[(size_t)(i + 3) * D_H + j];
        #pragma unroll
        for (int nb = 0; nb < 8; nb++) {
            float4 xx = *(const float4*)&sx[nb][i];
            float tl = accl[nb], tr = accr[nb];
            tl = fmaf(xx.x, wl0, tl); tl = fmaf(xx.y, wl1, tl);
            tl = fmaf(xx.z, wl2, tl); tl = fmaf(xx.w, wl3, tl);
            tr = fmaf(xx.x, wr0, tr); tr = fmaf(xx.y, wr1, tr);
            tr = fmaf(xx.z, wr2, tr); tr = fmaf(xx.w, wr3, tr);
            accl[nb] = tl; accr[nb] = tr;
        }
    }
    for (int nb = 0; nb < 8; nb++) {
        int n = nb0 + nb;
        if (n < N_NODES) {
            xw1[(size_t)n * D_H + j] = accl[nb];
            xwr[(size_t)n * D_H + j] = accr[nb];
        }
    }
}

// ---------------- fused: h = elu(mean(xw1[nbr]) + b1 + xwr); en/enb = normalize(h);
//                  out_h = h; hwl = h @ W2_l^T; hwr = h @ W2_r^T ----------------
__global__ __launch_bounds__(256) void gather_h_fused_kernel(const float* __restrict__ xw1,
        const float* __restrict__ xwr, const int* __restrict__ nbr,
        const int* __restrict__ rowptr, const int* __restrict__ cnt,
        const float* __restrict__ b1, const float* __restrict__ W2lT,
        const float* __restrict__ W2rT, float* __restrict__ h, float* __restrict__ en,
        unsigned short* __restrict__ enb, float* __restrict__ outh,
        float* __restrict__ hwl, float* __restrict__ hwr) {
    __shared__ float sh[4][D_H];
    int wid = threadIdx.x >> 6, lane = threadIdx.x & 63;
    int n = blockIdx.x * 4 + wid;
    if (n >= N_NODES) return;
    int st = rowptr[n], deg = cnt[n];
    float a[4] = {0,0,0,0};
    for (int j = 0; j < deg; j++) {
        int s = nbr[st + j];
        float4 v = *(const float4*)&xw1[(size_t)s * D_H + lane * 4];
        a[0] += v.x; a[1] += v.y; a[2] += v.z; a[3] += v.w;
    }
    float inv = 1.0f / fmaxf((float)deg, 1.0f);
    float4 r4 = *(const float4*)&xwr[(size_t)n * D_H + lane * 4];
    float4 bb = *(const float4*)&b1[lane * 4];
    float o0 = a[0] * inv + bb.x + r4.x;
    float o1 = a[1] * inv + bb.y + r4.y;
    float o2 = a[2] * inv + bb.z + r4.z;
    float o3 = a[3] * inv + bb.w + r4.w;
    o0 = o0 > 0.f ? o0 : expm1f(o0);
    o1 = o1 > 0.f ? o1 : expm1f(o1);
    o2 = o2 > 0.f ? o2 : expm1f(o2);
    o3 = o3 > 0.f ? o3 : expm1f(o3);
    float4 hv = make_float4(o0, o1, o2, o3);
    *(float4*)&h[(size_t)n * D_H + lane * 4] = hv;
    *(float4*)&outh[(size_t)n * D_H + lane * 4] = hv;
    *(float4*)&sh[wid][lane * 4] = hv;          // wave-private row; no block sync needed

    // norm -> en (fp32) + enb (bf16)
    float ss = o0 * o0 + o1 * o1 + o2 * o2 + o3 * o3;
    for (int o = 32; o; o >>= 1) ss += __shfl_xor(ss, o);
    float ninv = 1.0f / fmaxf(sqrtf(ss), 1e-8f);
    float e[4] = {o0 * ninv, o1 * ninv, o2 * ninv, o3 * ninv};
    *(float4*)&en[(size_t)n * D_H + lane * 4] = make_float4(e[0], e[1], e[2], e[3]);
    unsigned int p[4];
    #pragma unroll
    for (int k = 0; k < 4; k++) {
        unsigned int ub = __float_as_uint(e[k]);
        p[k] = (ub + 0x7FFFu + ((ub >> 16) & 1u)) >> 16;   // RNE to bf16
    }
    uint2 packed = make_uint2(p[0] | (p[1] << 16), p[2] | (p[3] << 16));
    *(uint2*)&enb[(size_t)n * D_H + lane * 4] = packed;

    // proj2: hwl/hwr for own node (lanes 0..39)
    if (lane < NCLS) {
        float al = 0.f, ar = 0.f;
        for (int i = 0; i < D_H; i++) {
            float hvv = sh[wid][i];
            al = fmaf(hvv, W2lT[(size_t)i * NCLS + lane], al);
            ar = fmaf(hvv, W2rT[(size_t)i * NCLS + lane], ar);
        }
        hwl[(size_t)n * NCLS + lane] = al;
        hwr[(size_t)n * NCLS + lane] = ar;
    }
}

// ---------------- lcls = log_softmax(elu(mean(hwl[nbr]) + b2 + hwr)) ----------------
__global__ void gather_lc_kernel(const float* __restrict__ hwl, const float* __restrict__ hwr,
                                 const int* __restrict__ nbr, const int* __restrict__ rowptr,
                                 const int* __restrict__ cnt, const float* __restrict__ b2,
                                 float* __restrict__ lcls) {
    int wid = threadIdx.x >> 6, lane = threadIdx.x & 63;
    int n = blockIdx.x * 4 + wid;
    if (n >= N_NODES) return;
    int st = rowptr[n], deg = cnt[n];
    float a = 0.f;
    if (lane < NCLS) {
        for (int j = 0; j < deg; j++) {
            int s = nbr[st + j];
            a += hwl[(size_t)s * NCLS + lane];
        }
    }
    float inv = 1.0f / fmaxf((float)deg, 1.0f);
    float v;
    if (lane < NCLS) {
        v = a * inv + b2[lane] + hwr[(size_t)n * NCLS + lane];
        v = v > 0.f ? v : expm1f(v);
    } else {
        v = -INFINITY;
    }
    float m = v;
    for (int o = 32; o; o >>= 1) m = fmaxf(m, __shfl_xor(m, o));
    float ex = (lane < NCLS) ? expf(v - m) : 0.0f;
    float s = ex;
    for (int o = 32; o; o >>= 1) s += __shfl_xor(s, o);
    if (lane < NCLS) lcls[(size_t)n * NCLS + lane] = v - m - logf(s);
}

// ---------------- MFMA bf16 prefilter, ring-3 LDS + counted vmcnt (R13 structure) ----------------
// R15: pv/pi stored STREAM-MAJOR ([r][stream*SLOTS+k]) -> dense 24B writes per lane,
// dense reads in rescore. Values and selection identical to R13.
__global__ __launch_bounds__(256) void sim_topk_kernel(const unsigned short* __restrict__ enb,
        const float* __restrict__ mask, float* __restrict__ pv, int* __restrict__ pi) {
    __shared__ __align__(16) char Abuf[3][8192];   // 3 x 8KB ring

    int rt = blockIdx.x / CSPL, cs = blockIdx.x % CSPL;
    int tid = threadIdx.x;
    int w = tid >> 6, l = tid & 63;
    int l15 = l & 15, lh = l >> 4;            // lh: 0..3
    int r = rt * ROWS + w * 16 + l15;         // this lane's sim row
    int rc = (r < N_NODES) ? r : (N_NODES - 1);

    // contiguous fragment chunk: cs=0 -> [0,49), cs>=1 -> [48cs+1, 48cs+49)
    int fbeg = cs * 48 + (cs ? 1 : 0);
    int fend = fbeg + (cs ? 48 : 49);

    // B fragments: own row of enb, full K=256
    bf16x8 bfr[8];
    const unsigned short* brow = enb + (size_t)rc * D_H + 8 * lh;
    #pragma unroll
    for (int ks = 0; ks < 8; ks++) bfr[ks] = *(const bf16x8*)(brow + ks * 32);

    float tv[SLOTS]; int ti[SLOTS];
    #pragma unroll
    for (int k = 0; k < SLOTS; k++) { tv[k] = -INFINITY; ti[k] = 0; }

    const float* mrow = mask + (size_t)rc * N_NODES;

    // swizzled ds_read byte offsets within a tile (8, per-lane constants)
    int offs[8];
    {
        int swz = (l15 & 7) << 4;
        #pragma unroll
        for (int ks = 0; ks < 8; ks++) offs[ks] = (lh * 16 + ks * 64) ^ swz;
    }

    // staging geometry: wave w covers tile bytes [w*2048, w*2048+2048) in 2 gload_lds.
    int row0 = 4 * w + (l >> 5);
    int row1 = row0 + 2;
    int tcol = l & 31;
    int g0 = tcol ^ (row0 & 7);
    int g1 = tcol ^ (row1 & 7);
    const char* gB = (const char*)enb;
    char* lds0 = &Abuf[0][0];

    // prologue: stage fbeg -> buf0, fbeg+1 -> buf1 (chunk length >= 48 so fbeg+1 < fend)
    gload_lds16(gB + (((size_t)(fbeg * 16 + row0)) << 9) + g0 * 16, lds0 + w * 2048);
    gload_lds16(gB + (((size_t)(fbeg * 16 + row1)) << 9) + g1 * 16, lds0 + w * 2048 + 1024);
    gload_lds16(gB + (((size_t)((fbeg + 1) * 16 + row0)) << 9) + g0 * 16, lds0 + 8192 + w * 2048);
    gload_lds16(gB + (((size_t)((fbeg + 1) * 16 + row1)) << 9) + g1 * 16, lds0 + 8192 + w * 2048 + 1024);

    float4 mm  = *(const float4*)&mrow[fbeg * 16 + lh * 4];
    float4 mm1 = *(const float4*)&mrow[(fbeg + 1) * 16 + lh * 4];

    int cur = 0;
    for (int f = fbeg; f < fend; ++f) {
        bool more = (f + 1 < fend);            // uniform across block
        // [A] own tile-f loads complete (counted; never 0 mid-loop)
        if (more) asm volatile("s_waitcnt vmcnt(2)" ::: "memory");
        else      asm volatile("s_waitcnt vmcnt(0)" ::: "memory");
        // [B] all waves' tile-f loads landed; all waves done reading buf[(cur+2)%3]'s old tile
        __builtin_amdgcn_s_barrier();
        __builtin_amdgcn_sched_barrier(0);
        // [C] issue tile f+2 into the freed buffer; prefetch mask f+2
        float4 mm2 = make_float4(0.f, 0.f, 0.f, 0.f);
        if (f + 2 < fend) {
            int nb = cur + 2; nb = (nb >= 3) ? nb - 3 : nb;
            char* dst = lds0 + nb * 8192 + w * 2048;
            gload_lds16(gB + (((size_t)((f + 2) * 16 + row0)) << 9) + g0 * 16, dst);
            gload_lds16(gB + (((size_t)((f + 2) * 16 + row1)) << 9) + g1 * 16, dst + 1024);
            mm2 = *(const float4*)&mrow[(f + 2) * 16 + lh * 4];
        }
        // [D] compute on buf[cur]
        const char* lbase = lds0 + cur * 8192 + l15 * 512;
        f32x4 acc = {0.f, 0.f, 0.f, 0.f};
        #pragma unroll
        for (int ks = 0; ks < 8; ks++) {
            bf16x8 af = *(const bf16x8*)(lbase + offs[ks]);
            acc = __builtin_amdgcn_mfma_f32_16x16x32_bf16(af, bfr[ks], acc, 0, 0, 0);
        }

        int c0 = f * 16 + lh * 4;
        float vv[4];
        vv[0] = acc[0] * mm.x; vv[1] = acc[1] * mm.y;
        vv[2] = acc[2] * mm.z; vv[3] = acc[3] * mm.w;
        // branchless top-6 insert, shared compares; strict > keeps earliest col on ties
        #pragma unroll
        for (int j = 0; j < 4; j++) {
            float v = vv[j]; int c = c0 + j;
            bool hh[SLOTS];
            #pragma unroll
            for (int k = 0; k < SLOTS; k++) hh[k] = tv[k] < v;
            float nv[SLOTS]; int ni[SLOTS];
            #pragma unroll
            for (int k = 0; k < SLOTS - 1; k++) {
                nv[k] = hh[k + 1] ? tv[k + 1] : (hh[k] ? v : tv[k]);
                ni[k] = hh[k + 1] ? ti[k + 1] : (hh[k] ? c : ti[k]);
            }
            nv[SLOTS - 1] = hh[SLOTS - 1] ? v : tv[SLOTS - 1];
            ni[SLOTS - 1] = hh[SLOTS - 1] ? c : ti[SLOTS - 1];
            #pragma unroll
            for (int k = 0; k < SLOTS; k++) { tv[k] = nv[k]; ti[k] = ni[k]; }
        }

        mm = mm1; mm1 = mm2;
        cur = (cur == 2) ? 0 : cur + 1;
    }

    if (r < N_NODES) {
        int stream = cs * 4 + lh;              // 0..51 lane-stream id
        float* pvp = pv + (size_t)r * CPR + stream * SLOTS;   // stream-major, dense
        int*   pip = pi + (size_t)r * CPR + stream * SLOTS;
        #pragma unroll
        for (int k = 0; k < SLOTS; k++) { pvp[k] = tv[k]; pip[k] = ti[k]; }
    }
}

// ---------------- top-32 by bf16 value -> exact fp32 rescore -> top-16 -> fusion -> blend ----------------
__global__ __launch_bounds__(256) void rescore_merge_kernel(const float* __restrict__ en,
        const float* __restrict__ mask, const float* __restrict__ pv, const int* __restrict__ pi,
        const int* __restrict__ y, const float* __restrict__ lcls, float* __restrict__ out) {
    __shared__ float sen[4][D_H];
    int wid = threadIdx.x >> 6, lane = threadIdx.x & 63;
    int r = blockIdx.x * 4 + wid;
    if (r >= N_NODES) return;
    *(float4*)&sen[wid][lane * 4] = *(const float4*)&en[(size_t)r * D_H + lane * 4];

    // ---- Phase A: lanes 0..51 own stream `lane` (6 ascending slots, dense); pick row top-32 ----
    float v0 = -INFINITY, v1 = -INFINITY, v2 = -INFINITY;
    float v3 = -INFINITY, v4 = -INFINITY, v5 = -INFINITY;
    int   i0 = 0x7FFFFFFF, i1 = 0x7FFFFFFF, i2 = 0x7FFFFFFF;
    int   i3 = 0x7FFFFFFF, i4 = 0x7FFFFFFF, i5 = 0x7FFFFFFF;
    if (lane < LSTREAM) {
        const float* pvr = pv + (size_t)r * CPR + lane * SLOTS;
        const int*   pir = pi + (size_t)r * CPR + lane * SLOTS;
        v0 = pvr[0]; v1 = pvr[1]; v2 = pvr[2];
        v3 = pvr[3]; v4 = pvr[4]; v5 = pvr[5];
        i0 = pir[0]; i1 = pir[1]; i2 = pir[2];
        i3 = pir[3]; i4 = pir[4]; i5 = pir[5];
    }
    int p = SLOTS - 1;              // pointer to current lane max (slots ascending)
    int my_cand = 0;
    #pragma unroll 1
    for (int t = 0; t < RESC; t++) {
        float cur  = (p < 0) ? -INFINITY :
                     (p == 5 ? v5 : p == 4 ? v4 : p == 3 ? v3 : p == 2 ? v2 : p == 1 ? v1 : v0);
        int   curi = (p < 0) ? 0x7FFFFFFF :
                     (p == 5 ? i5 : p == 4 ? i4 : p == 3 ? i3 : p == 2 ? i2 : p == 1 ? i1 : i0);
        float rv = cur; int ri = curi;
        #pragma unroll
        for (int o = 1; o < 64; o <<= 1) {
            float ov = __shfl_xor(rv, o); int oi = __shfl_xor(ri, o);
            bool bet = (ov > rv) || (ov == rv && oi < ri);
            rv = bet ? ov : rv; ri = bet ? oi : ri;
        }
        if (curi == ri && p >= 0) p--;      // indices unique per row -> only winner decrements
        if (lane == t) my_cand = ri;
    }
    // broadcast: lane L and L+32 rescore candidate sel[L&31]
    int cand = __shfl(my_cand, lane & 31);
    cand = (cand >= 0 && cand < N_NODES) ? cand : 0;

    __syncthreads();   // sen ready

    // ---- Phase B: exact fp32 dot, 2 lanes per candidate (k-halves) ----
    int half = lane >> 5;               // 0 or 1
    const float* erow = &en[(size_t)cand * D_H + half * 128];
    const float* srow = &sen[wid][half * 128];
    float dot = 0.0f;
    #pragma unroll 8
    for (int k = 0; k < 128; k += 4) {
        float4 e = *(const float4*)&erow[k];
        dot = fmaf(srow[k + 0], e.x, dot);
        dot = fmaf(srow[k + 1], e.y, dot);
        dot = fmaf(srow[k + 2], e.z, dot);
        dot = fmaf(srow[k + 3], e.w, dot);
    }
    dot += __shfl_xor(dot, 32);
    float cv = (lane < RESC) ? dot * mask[(size_t)r * N_NODES + cand] : -INFINITY;

    // ---- Phase C: exact top-16 -> label fusion -> log-softmax -> blend ----
    float fc = 0.0f;
    #pragma unroll 1
    for (int t = 0; t < KTOP; t++) {
        float rv = cv; int ri = (lane < RESC) ? cand : 0x7FFFFFFF;
        #pragma unroll
        for (int o = 1; o < 64; o <<= 1) {
            float ov = __shfl_xor(rv, o); int oi = __shfl_xor(ri, o);
            bool bet = (ov > rv) || (ov == rv && oi < ri);
            rv = bet ? ov : rv; ri = bet ? oi : ri;
        }
        if (lane < RESC && cand == ri) cv = -INFINITY;
        int ris = (ri >= 0 && ri < N_NODES) ? ri : 0;
        int lbl = y[ris];
        if (lane == lbl) fc += expf(rv);
    }
    float fval = (lane < NCLS) ? fc : -INFINITY;
    float m = fval;
    for (int o = 32; o; o >>= 1) m = fmaxf(m, __shfl_xor(m, o));
    float ex = (lane < NCLS) ? expf(fval - m) : 0.0f;
    float s = ex;
    for (int o = 32; o; o >>= 1) s += __shfl_xor(s, o);
    if (lane < NCLS)
        out[(size_t)r * NCLS + lane] = 0.5f * lcls[(size_t)r * NCLS + lane]
                                     + 0.5f * (fval - m - logf(s));
}

extern "C" void kernel_launch(void* const* d_in, const int* in_sizes, int n_in,
                              void* d_out, int out_size, void* d_ws, size_t ws_size,
                              hipStream_t stream) {
    const float* x    = (const float*)d_in[0];
    const int*   ei   = (const int*)  d_in[1];
    const int*   y    = (const int*)  d_in[2];
    const float* mask = (const float*)d_in[3];
    const float* W1_l = (const float*)d_in[4];
    const float* b1   = (const float*)d_in[5];
    const float* W1_r = (const float*)d_in[6];
    const float* W2_l = (const float*)d_in[7];
    const float* b2   = (const float*)d_in[8];
    const float* W2_r = (const float*)d_in[9];

    float* out   = (float*)d_out;
    float* out_h = out + (size_t)N_NODES * NCLS;

    int*   cnt    = (int*)d_ws;                       // 10240
    int*   rowptr = cnt + 10240;                      // 10304
    int*   cursor = rowptr + 10304;                   // 10240
    int*   nbr    = cursor + 10240;                   // 160256
    float* xw1    = (float*)(nbr + 160256);           // N*256
    float* xwr    = xw1 + (size_t)N_NODES * D_H;      // N*256
    float* h      = xwr + (size_t)N_NODES * D_H;      // N*256
    float* en     = h   + (size_t)N_NODES * D_H;      // N*256
    unsigned short* enb = (unsigned short*)(en + (size_t)N_NODES * D_H);  // N*256 bf16
    float* lcls   = (float*)(enb + (size_t)N_NODES * D_H);                // N*40
    float* hwl    = lcls + (size_t)N_NODES * NCLS;    // N*40
    float* hwr    = hwl + (size_t)N_NODES * NCLS;     // N*40
    float* W1lT   = hwr + (size_t)N_NODES * NCLS;
    float* W1rT   = W1lT + (size_t)D_IN * D_H;
    float* W2lT   = W1rT + (size_t)D_IN * D_H;
    float* W2rT   = W2lT + (size_t)D_H * NCLS;
    // pv aliases xw1+xwr (N*512 floats, dead after gather_h_fused which runs before sim_topk)
    float* pv     = xw1;                                 // N*312 used
    int*   pi     = (int*)(W2rT + (size_t)D_H * NCLS);   // N*312 used

    const int* src = ei;
    const int* dst = ei + NEDGE;

    hipMemsetAsync(cnt, 0, 10240 * sizeof(int), stream);

    transpose_kernel<<<(D_H * D_IN + 255) / 256, 256, 0, stream>>>(
        W1_l, W1_r, W2_l, W2_r, W1lT, W1rT, W2lT, W2rT);
    count_kernel<<<(NEDGE + 255) / 256, 256, 0, stream>>>(dst, cnt);
    prefix_kernel<<<1, 256, 0, stream>>>(cnt, rowptr, cursor);
    bucket_kernel<<<(NEDGE + 255) / 256, 256, 0, stream>>>(src, dst, cursor, nbr);
    proj1_kernel<<<(N_NODES + 7) / 8, 256, 0, stream>>>(x, W1lT, W1rT, xw1, xwr);
    gather_h_fused_kernel<<<(N_NODES + 3) / 4, 256, 0, stream>>>(
        xw1, xwr, nbr, rowptr, cnt, b1, W2lT, W2rT, h, en, enb, out_h, hwl, hwr);
    gather_lc_kernel<<<(N_NODES + 3) / 4, 256, 0, stream>>>(hwl, hwr, nbr, rowptr, cnt, b2, lcls);
    sim_topk_kernel<<<RT * CSPL, 256, 0, stream>>>(enb, mask, pv, pi);
    rescore_merge_kernel<<<(N_NODES + 3) / 4, 256, 0, stream>>>(en, mask, pv, pi, y, lcls, out);
}

// Round 16
// 470.886 us; speedup vs baseline: 1.1118x; 1.0455x over previous
//
#include <hip/hip_runtime.h>
#include <math.h>

#define N_NODES 10000
#define D_IN    512
#define D_H     256
#define NCLS    40
#define NEDGE   160000
#define KTOP    16
#define NFRAG   625            // 10000 / 16 column fragments
#define CSPL    13             // column splits
#define ROWS    64             // rows per block (16 per wave)
#define RT      157            // ceil(10000/64) row tiles
#define SLOTS   6              // per-lane-stream top-6
#define LSTREAM 52             // lane-streams per row = CSPL * 4 lh-groups
#define CPR     (LSTREAM * SLOTS)   // candidates per row = 312
#define RESC    24             // exactly-rescored candidates per row (bf16 top-24)

typedef __attribute__((ext_vector_type(8))) short bf16x8;
typedef __attribute__((ext_vector_type(4))) float f32x4;

__device__ __forceinline__ void gload_lds16(const void* g, void* l) {
    __builtin_amdgcn_global_load_lds(
        (const __attribute__((address_space(1))) void*)g,
        (__attribute__((address_space(3))) void*)l, 16, 0, 0);
}

// ---------------- transpose weights + degree count (fused, disjoint index ranges) ----------------
__global__ void transpose_count_kernel(const float* __restrict__ W1_l, const float* __restrict__ W1_r,
                                       const float* __restrict__ W2_l, const float* __restrict__ W2_r,
                                       float* __restrict__ W1lT, float* __restrict__ W1rT,
                                       float* __restrict__ W2lT, float* __restrict__ W2rT,
                                       const int* __restrict__ dst, int* __restrict__ cnt) {
    int i = blockIdx.x * 256 + threadIdx.x;
    if (i < D_H * D_IN) {
        int r = i / D_IN, c = i % D_IN;
        W1lT[(size_t)c * D_H + r] = W1_l[i];
        W1rT[(size_t)c * D_H + r] = W1_r[i];
    }
    if (i < NCLS * D_H) {
        int r = i / D_H, c = i % D_H;
        W2lT[(size_t)c * NCLS + r] = W2_l[i];
        W2rT[(size_t)c * NCLS + r] = W2_r[i];
    }
    if (i < NEDGE) {
        int d = dst[i];
        d = (d >= 0 && d < N_NODES) ? d : 0;
        atomicAdd(&cnt[d], 1);
    }
}

// ---------------- prefix scan -> rowptr, cursor ----------------
__global__ void prefix_kernel(const int* __restrict__ cnt, int* __restrict__ rowptr,
                              int* __restrict__ cursor) {
    __shared__ int sp[256];
    int t = threadIdx.x;
    int b0 = t * 40;
    int e0 = (b0 + 40 < N_NODES) ? b0 + 40 : N_NODES;
    int s = 0;
    for (int i = b0; i < e0; i++) s += cnt[i];
    sp[t] = s;
    __syncthreads();
    for (int o = 1; o < 256; o <<= 1) {
        int add = (t >= o) ? sp[t - o] : 0;
        __syncthreads();
        sp[t] += add;
        __syncthreads();
    }
    int run = sp[t] - s;     // exclusive prefix
    for (int i = b0; i < e0; i++) {
        rowptr[i] = run; cursor[i] = run; run += cnt[i];
    }
    if (t == 255) rowptr[N_NODES] = run;
}

// ---------------- bucket edges by dst ----------------
__global__ void bucket_kernel(const int* __restrict__ src, const int* __restrict__ dst,
                              int* __restrict__ cursor, int* __restrict__ nbr) {
    int e = blockIdx.x * 256 + threadIdx.x;
    if (e < NEDGE) {
        int d = dst[e];
        d = (d >= 0 && d < N_NODES) ? d : 0;
        int p = atomicAdd(&cursor[d], 1);
        if (p >= 0 && p < NEDGE) {
            int s = src[e];
            nbr[p] = (s >= 0 && s < N_NODES) ? s : 0;
        }
    }
}

// ---------------- xw1 = x @ W1_l^T ; xwr = x @ W1_r^T ----------------
__global__ __launch_bounds__(256) void proj1_kernel(const float* __restrict__ x,
        const float* __restrict__ W1lT, const float* __restrict__ W1rT,
        float* __restrict__ xw1, float* __restrict__ xwr) {
    __shared__ float sx[8][D_IN];
    int tid = threadIdx.x;
    int nb0 = blockIdx.x * 8;
    #pragma unroll
    for (int u = 0; u < 4; u++) {
        int s = tid + u * 256;          // 0..1023
        int nb = s >> 7;                // 0..7
        int c4 = (s & 127) << 2;        // 0..508
        int n = nb0 + nb;
        float4 v = make_float4(0.f, 0.f, 0.f, 0.f);
        if (n < N_NODES) v = *(const float4*)&x[(size_t)n * D_IN + c4];
        *(float4*)&sx[nb][c4] = v;
    }
    __syncthreads();
    int j = tid;
    float accl[8] = {0,0,0,0,0,0,0,0};
    float accr[8] = {0,0,0,0,0,0,0,0};
    for (int i = 0; i < D_IN; i += 4) {
        float wl0 = W1lT[(size_t)(i + 0) * D_H + j];
        float wl1 = W1lT[(size_t)(i + 1) * D_H + j];
        float wl2 = W1lT[(size_t)(i + 2) * D_H + j];
        float wl3 = W1lT[(size_t)(i + 3) * D_H + j];
        float wr0 = W1rT[(size_t)(i + 0) * D_H + j];
        float wr1 = W1rT[(size_t)(i + 1) * D_H + j];
        float wr2 = W1rT[(size_t)(i + 2) * D_H + j];
        float wr3 = W1rT[(size_t)(i + 3) * D_H + j];
        #pragma unroll
        for (int nb = 0; nb < 8; nb++) {
            float4 xx = *(const float4*)&sx[nb][i];
            float tl = accl[nb], tr = accr[nb];
            tl = fmaf(xx.x, wl0, tl); tl = fmaf(xx.y, wl1, tl);
            tl = fmaf(xx.z, wl2, tl); tl = fmaf(xx.w, wl3, tl);
            tr = fmaf(xx.x, wr0, tr); tr = fmaf(xx.y, wr1, tr);
            tr = fmaf(xx.z, wr2, tr); tr = fmaf(xx.w, wr3, tr);
            accl[nb] = tl; accr[nb] = tr;
        }
    }
    for (int nb = 0; nb < 8; nb++) {
        int n = nb0 + nb;
        if (n < N_NODES) {
            xw1[(size_t)n * D_H + j] = accl[nb];
            xwr[(size_t)n * D_H + j] = accr[nb];
        }
    }
}

// ---------------- fused: h = elu(mean(xw1[nbr]) + b1 + xwr); en/enb = normalize(h);
//                  out_h = h; hwl = h @ W2_l^T; hwr = h @ W2_r^T ----------------
__global__ __launch_bounds__(256) void gather_h_fused_kernel(const float* __restrict__ xw1,
        const float* __restrict__ xwr, const int* __restrict__ nbr,
        const int* __restrict__ rowptr, const int* __restrict__ cnt,
        const float* __restrict__ b1, const float* __restrict__ W2lT,
        const float* __restrict__ W2rT, float* __restrict__ h, float* __restrict__ en,
        unsigned short* __restrict__ enb, float* __restrict__ outh,
        float* __restrict__ hwl, float* __restrict__ hwr) {
    __shared__ float sh[4][D_H];
    int wid = threadIdx.x >> 6, lane = threadIdx.x & 63;
    int n = blockIdx.x * 4 + wid;
    if (n >= N_NODES) return;
    int st = rowptr[n], deg = cnt[n];
    float a[4] = {0,0,0,0};
    for (int j = 0; j < deg; j++) {
        int s = nbr[st + j];
        float4 v = *(const float4*)&xw1[(size_t)s * D_H + lane * 4];
        a[0] += v.x; a[1] += v.y; a[2] += v.z; a[3] += v.w;
    }
    float inv = 1.0f / fmaxf((float)deg, 1.0f);
    float4 r4 = *(const float4*)&xwr[(size_t)n * D_H + lane * 4];
    float4 bb = *(const float4*)&b1[lane * 4];
    float o0 = a[0] * inv + bb.x + r4.x;
    float o1 = a[1] * inv + bb.y + r4.y;
    float o2 = a[2] * inv + bb.z + r4.z;
    float o3 = a[3] * inv + bb.w + r4.w;
    o0 = o0 > 0.f ? o0 : expm1f(o0);
    o1 = o1 > 0.f ? o1 : expm1f(o1);
    o2 = o2 > 0.f ? o2 : expm1f(o2);
    o3 = o3 > 0.f ? o3 : expm1f(o3);
    float4 hv = make_float4(o0, o1, o2, o3);
    *(float4*)&h[(size_t)n * D_H + lane * 4] = hv;
    *(float4*)&outh[(size_t)n * D_H + lane * 4] = hv;
    *(float4*)&sh[wid][lane * 4] = hv;          // wave-private row; no block sync needed

    // norm -> en (fp32) + enb (bf16)
    float ss = o0 * o0 + o1 * o1 + o2 * o2 + o3 * o3;
    for (int o = 32; o; o >>= 1) ss += __shfl_xor(ss, o);
    float ninv = 1.0f / fmaxf(sqrtf(ss), 1e-8f);
    float e[4] = {o0 * ninv, o1 * ninv, o2 * ninv, o3 * ninv};
    *(float4*)&en[(size_t)n * D_H + lane * 4] = make_float4(e[0], e[1], e[2], e[3]);
    unsigned int p[4];
    #pragma unroll
    for (int k = 0; k < 4; k++) {
        unsigned int ub = __float_as_uint(e[k]);
        p[k] = (ub + 0x7FFFu + ((ub >> 16) & 1u)) >> 16;   // RNE to bf16
    }
    uint2 packed = make_uint2(p[0] | (p[1] << 16), p[2] | (p[3] << 16));
    *(uint2*)&enb[(size_t)n * D_H + lane * 4] = packed;

    // proj2: hwl/hwr for own node (lanes 0..39)
    if (lane < NCLS) {
        float al = 0.f, ar = 0.f;
        for (int i = 0; i < D_H; i++) {
            float hvv = sh[wid][i];
            al = fmaf(hvv, W2lT[(size_t)i * NCLS + lane], al);
            ar = fmaf(hvv, W2rT[(size_t)i * NCLS + lane], ar);
        }
        hwl[(size_t)n * NCLS + lane] = al;
        hwr[(size_t)n * NCLS + lane] = ar;
    }
}

// ---------------- lcls = log_softmax(elu(mean(hwl[nbr]) + b2 + hwr)) ----------------
__global__ void gather_lc_kernel(const float* __restrict__ hwl, const float* __restrict__ hwr,
                                 const int* __restrict__ nbr, const int* __restrict__ rowptr,
                                 const int* __restrict__ cnt, const float* __restrict__ b2,
                                 float* __restrict__ lcls) {
    int wid = threadIdx.x >> 6, lane = threadIdx.x & 63;
    int n = blockIdx.x * 4 + wid;
    if (n >= N_NODES) return;
    int st = rowptr[n], deg = cnt[n];
    float a = 0.f;
    if (lane < NCLS) {
        for (int j = 0; j < deg; j++) {
            int s = nbr[st + j];
            a += hwl[(size_t)s * NCLS + lane];
        }
    }
    float inv = 1.0f / fmaxf((float)deg, 1.0f);
    float v;
    if (lane < NCLS) {
        v = a * inv + b2[lane] + hwr[(size_t)n * NCLS + lane];
        v = v > 0.f ? v : expm1f(v);
    } else {
        v = -INFINITY;
    }
    float m = v;
    for (int o = 32; o; o >>= 1) m = fmaxf(m, __shfl_xor(m, o));
    float ex = (lane < NCLS) ? expf(v - m) : 0.0f;
    float s = ex;
    for (int o = 32; o; o >>= 1) s += __shfl_xor(s, o);
    if (lane < NCLS) lcls[(size_t)n * NCLS + lane] = v - m - logf(s);
}

// ---------------- MFMA bf16 prefilter, ring-3 LDS + counted vmcnt (R13/R15 structure) ----------------
// pv/pi stored STREAM-MAJOR ([r][stream*SLOTS+k]) -> dense 24B writes per lane.
__global__ __launch_bounds__(256) void sim_topk_kernel(const unsigned short* __restrict__ enb,
        const float* __restrict__ mask, float* __restrict__ pv, int* __restrict__ pi) {
    __shared__ __align__(16) char Abuf[3][8192];   // 3 x 8KB ring

    int rt = blockIdx.x / CSPL, cs = blockIdx.x % CSPL;
    int tid = threadIdx.x;
    int w = tid >> 6, l = tid & 63;
    int l15 = l & 15, lh = l >> 4;            // lh: 0..3
    int r = rt * ROWS + w * 16 + l15;         // this lane's sim row
    int rc = (r < N_NODES) ? r : (N_NODES - 1);

    // contiguous fragment chunk: cs=0 -> [0,49), cs>=1 -> [48cs+1, 48cs+49)
    int fbeg = cs * 48 + (cs ? 1 : 0);
    int fend = fbeg + (cs ? 48 : 49);

    // B fragments: own row of enb, full K=256
    bf16x8 bfr[8];
    const unsigned short* brow = enb + (size_t)rc * D_H + 8 * lh;
    #pragma unroll
    for (int ks = 0; ks < 8; ks++) bfr[ks] = *(const bf16x8*)(brow + ks * 32);

    float tv[SLOTS]; int ti[SLOTS];
    #pragma unroll
    for (int k = 0; k < SLOTS; k++) { tv[k] = -INFINITY; ti[k] = 0; }

    const float* mrow = mask + (size_t)rc * N_NODES;

    // swizzled ds_read byte offsets within a tile (8, per-lane constants)
    int offs[8];
    {
        int swz = (l15 & 7) << 4;
        #pragma unroll
        for (int ks = 0; ks < 8; ks++) offs[ks] = (lh * 16 + ks * 64) ^ swz;
    }

    // staging geometry: wave w covers tile bytes [w*2048, w*2048+2048) in 2 gload_lds.
    int row0 = 4 * w + (l >> 5);
    int row1 = row0 + 2;
    int tcol = l & 31;
    int g0 = tcol ^ (row0 & 7);
    int g1 = tcol ^ (row1 & 7);
    const char* gB = (const char*)enb;
    char* lds0 = &Abuf[0][0];

    // prologue: stage fbeg -> buf0, fbeg+1 -> buf1 (chunk length >= 48 so fbeg+1 < fend)
    gload_lds16(gB + (((size_t)(fbeg * 16 + row0)) << 9) + g0 * 16, lds0 + w * 2048);
    gload_lds16(gB + (((size_t)(fbeg * 16 + row1)) << 9) + g1 * 16, lds0 + w * 2048 + 1024);
    gload_lds16(gB + (((size_t)((fbeg + 1) * 16 + row0)) << 9) + g0 * 16, lds0 + 8192 + w * 2048);
    gload_lds16(gB + (((size_t)((fbeg + 1) * 16 + row1)) << 9) + g1 * 16, lds0 + 8192 + w * 2048 + 1024);

    float4 mm  = *(const float4*)&mrow[fbeg * 16 + lh * 4];
    float4 mm1 = *(const float4*)&mrow[(fbeg + 1) * 16 + lh * 4];

    int cur = 0;
    for (int f = fbeg; f < fend; ++f) {
        bool more = (f + 1 < fend);            // uniform across block
        // [A] own tile-f loads complete (counted; never 0 mid-loop)
        if (more) asm volatile("s_waitcnt vmcnt(2)" ::: "memory");
        else      asm volatile("s_waitcnt vmcnt(0)" ::: "memory");
        // [B] all waves' tile-f loads landed; all waves done reading buf[(cur+2)%3]'s old tile
        __builtin_amdgcn_s_barrier();
        __builtin_amdgcn_sched_barrier(0);
        // [C] issue tile f+2 into the freed buffer; prefetch mask f+2
        float4 mm2 = make_float4(0.f, 0.f, 0.f, 0.f);
        if (f + 2 < fend) {
            int nb = cur + 2; nb = (nb >= 3) ? nb - 3 : nb;
            char* dst2 = lds0 + nb * 8192 + w * 2048;
            gload_lds16(gB + (((size_t)((f + 2) * 16 + row0)) << 9) + g0 * 16, dst2);
            gload_lds16(gB + (((size_t)((f + 2) * 16 + row1)) << 9) + g1 * 16, dst2 + 1024);
            mm2 = *(const float4*)&mrow[(f + 2) * 16 + lh * 4];
        }
        // [D] compute on buf[cur]
        const char* lbase = lds0 + cur * 8192 + l15 * 512;
        f32x4 acc = {0.f, 0.f, 0.f, 0.f};
        #pragma unroll
        for (int ks = 0; ks < 8; ks++) {
            bf16x8 af = *(const bf16x8*)(lbase + offs[ks]);
            acc = __builtin_amdgcn_mfma_f32_16x16x32_bf16(af, bfr[ks], acc, 0, 0, 0);
        }

        int c0 = f * 16 + lh * 4;
        float vv[4];
        vv[0] = acc[0] * mm.x; vv[1] = acc[1] * mm.y;
        vv[2] = acc[2] * mm.z; vv[3] = acc[3] * mm.w;
        // branchless top-6 insert, shared compares; strict > keeps earliest col on ties
        #pragma unroll
        for (int j = 0; j < 4; j++) {
            float v = vv[j]; int c = c0 + j;
            bool hh[SLOTS];
            #pragma unroll
            for (int k = 0; k < SLOTS; k++) hh[k] = tv[k] < v;
            float nv[SLOTS]; int ni[SLOTS];
            #pragma unroll
            for (int k = 0; k < SLOTS - 1; k++) {
                nv[k] = hh[k + 1] ? tv[k + 1] : (hh[k] ? v : tv[k]);
                ni[k] = hh[k + 1] ? ti[k + 1] : (hh[k] ? c : ti[k]);
            }
            nv[SLOTS - 1] = hh[SLOTS - 1] ? v : tv[SLOTS - 1];
            ni[SLOTS - 1] = hh[SLOTS - 1] ? c : ti[SLOTS - 1];
            #pragma unroll
            for (int k = 0; k < SLOTS; k++) { tv[k] = nv[k]; ti[k] = ni[k]; }
        }

        mm = mm1; mm1 = mm2;
        cur = (cur == 2) ? 0 : cur + 1;
    }

    if (r < N_NODES) {
        int stream = cs * 4 + lh;              // 0..51 lane-stream id
        float* pvp = pv + (size_t)r * CPR + stream * SLOTS;   // stream-major, dense
        int*   pip = pi + (size_t)r * CPR + stream * SLOTS;
        #pragma unroll
        for (int k = 0; k < SLOTS; k++) { pvp[k] = tv[k]; pip[k] = ti[k]; }
    }
}

// ---------------- top-24 by bf16 value -> exact fp32 rescore -> top-16 -> fusion -> blend ----------------
__global__ __launch_bounds__(256) void rescore_merge_kernel(const float* __restrict__ en,
        const float* __restrict__ mask, const float* __restrict__ pv, const int* __restrict__ pi,
        const int* __restrict__ y, const float* __restrict__ lcls, float* __restrict__ out) {
    __shared__ float sen[4][D_H];
    int wid = threadIdx.x >> 6, lane = threadIdx.x & 63;
    int r = blockIdx.x * 4 + wid;
    if (r >= N_NODES) return;
    *(float4*)&sen[wid][lane * 4] = *(const float4*)&en[(size_t)r * D_H + lane * 4];

    // ---- Phase A: lanes 0..51 own stream `lane` (6 ascending slots, dense); pick row top-24 ----
    float v0 = -INFINITY, v1 = -INFINITY, v2 = -INFINITY;
    float v3 = -INFINITY, v4 = -INFINITY, v5 = -INFINITY;
    int   i0 = 0x7FFFFFFF, i1 = 0x7FFFFFFF, i2 = 0x7FFFFFFF;
    int   i3 = 0x7FFFFFFF, i4 = 0x7FFFFFFF, i5 = 0x7FFFFFFF;
    if (lane < LSTREAM) {
        const float* pvr = pv + (size_t)r * CPR + lane * SLOTS;
        const int*   pir = pi + (size_t)r * CPR + lane * SLOTS;
        v0 = pvr[0]; v1 = pvr[1]; v2 = pvr[2];
        v3 = pvr[3]; v4 = pvr[4]; v5 = pvr[5];
        i0 = pir[0]; i1 = pir[1]; i2 = pir[2];
        i3 = pir[3]; i4 = pir[4]; i5 = pir[5];
    }
    int p = SLOTS - 1;              // pointer to current lane max (slots ascending)
    int my_cand = 0;
    #pragma unroll 1
    for (int t = 0; t < RESC; t++) {
        float cur  = (p < 0) ? -INFINITY :
                     (p == 5 ? v5 : p == 4 ? v4 : p == 3 ? v3 : p == 2 ? v2 : p == 1 ? v1 : v0);
        int   curi = (p < 0) ? 0x7FFFFFFF :
                     (p == 5 ? i5 : p == 4 ? i4 : p == 3 ? i3 : p == 2 ? i2 : p == 1 ? i1 : i0);
        float rv = cur; int ri = curi;
        #pragma unroll
        for (int o = 1; o < 64; o <<= 1) {
            float ov = __shfl_xor(rv, o); int oi = __shfl_xor(ri, o);
            bool bet = (ov > rv) || (ov == rv && oi < ri);
            rv = bet ? ov : rv; ri = bet ? oi : ri;
        }
        if (curi == ri && p >= 0) p--;      // indices unique per row -> only winner decrements
        if (lane == t) my_cand = ri;
    }
    // broadcast: lane L and L+32 rescore candidate sel[L&31] (valid for (L&31) < RESC)
    int cand = __shfl(my_cand, lane & 31);
    cand = (cand >= 0 && cand < N_NODES) ? cand : 0;

    __syncthreads();   // sen ready

    // ---- Phase B: exact fp32 dot, 2 lanes per candidate (k-halves) ----
    int half = lane >> 5;               // 0 or 1
    const float* erow = &en[(size_t)cand * D_H + half * 128];
    const float* srow = &sen[wid][half * 128];
    float dot = 0.0f;
    #pragma unroll 8
    for (int k = 0; k < 128; k += 4) {
        float4 e = *(const float4*)&erow[k];
        dot = fmaf(srow[k + 0], e.x, dot);
        dot = fmaf(srow[k + 1], e.y, dot);
        dot = fmaf(srow[k + 2], e.z, dot);
        dot = fmaf(srow[k + 3], e.w, dot);
    }
    dot += __shfl_xor(dot, 32);
    float cv = (lane < RESC) ? dot * mask[(size_t)r * N_NODES + cand] : -INFINITY;

    // ---- Phase C: exact top-16 -> label fusion -> log-softmax -> blend ----
    float fc = 0.0f;
    #pragma unroll 1
    for (int t = 0; t < KTOP; t++) {
        float rv = cv; int ri = (lane < RESC) ? cand : 0x7FFFFFFF;
        #pragma unroll
        for (int o = 1; o < 64; o <<= 1) {
            float ov = __shfl_xor(rv, o); int oi = __shfl_xor(ri, o);
            bool bet = (ov > rv) || (ov == rv && oi < ri);
            rv = bet ? ov : rv; ri = bet ? oi : ri;
        }
        if (lane < RESC && cand == ri) cv = -INFINITY;
        int ris = (ri >= 0 && ri < N_NODES) ? ri : 0;
        int lbl = y[ris];
        if (lane == lbl) fc += expf(rv);
    }
    float fval = (lane < NCLS) ? fc : -INFINITY;
    float m = fval;
    for (int o = 32; o; o >>= 1) m = fmaxf(m, __shfl_xor(m, o));
    float ex = (lane < NCLS) ? expf(fval - m) : 0.0f;
    float s = ex;
    for (int o = 32; o; o >>= 1) s += __shfl_xor(s, o);
    if (lane < NCLS)
        out[(size_t)r * NCLS + lane] = 0.5f * lcls[(size_t)r * NCLS + lane]
                                     + 0.5f * (fval - m - logf(s));
}

extern "C" void kernel_launch(void* const* d_in, const int* in_sizes, int n_in,
                              void* d_out, int out_size, void* d_ws, size_t ws_size,
                              hipStream_t stream) {
    const float* x    = (const float*)d_in[0];
    const int*   ei   = (const int*)  d_in[1];
    const int*   y    = (const int*)  d_in[2];
    const float* mask = (const float*)d_in[3];
    const float* W1_l = (const float*)d_in[4];
    const float* b1   = (const float*)d_in[5];
    const float* W1_r = (const float*)d_in[6];
    const float* W2_l = (const float*)d_in[7];
    const float* b2   = (const float*)d_in[8];
    const float* W2_r = (const float*)d_in[9];

    float* out   = (float*)d_out;
    float* out_h = out + (size_t)N_NODES * NCLS;

    int*   cnt    = (int*)d_ws;                       // 10240
    int*   rowptr = cnt + 10240;                      // 10304
    int*   cursor = rowptr + 10304;                   // 10240
    int*   nbr    = cursor + 10240;                   // 160256
    float* xw1    = (float*)(nbr + 160256);           // N*256
    float* xwr    = xw1 + (size_t)N_NODES * D_H;      // N*256
    float* h      = xwr + (size_t)N_NODES * D_H;      // N*256
    float* en     = h   + (size_t)N_NODES * D_H;      // N*256
    unsigned short* enb = (unsigned short*)(en + (size_t)N_NODES * D_H);  // N*256 bf16
    float* lcls   = (float*)(enb + (size_t)N_NODES * D_H);                // N*40
    float* hwl    = lcls + (size_t)N_NODES * NCLS;    // N*40
    float* hwr    = hwl + (size_t)N_NODES * NCLS;     // N*40
    float* W1lT   = hwr + (size_t)N_NODES * NCLS;
    float* W1rT   = W1lT + (size_t)D_IN * D_H;
    float* W2lT   = W1rT + (size_t)D_IN * D_H;
    float* W2rT   = W2lT + (size_t)D_H * NCLS;
    // pv aliases xw1+xwr (N*512 floats, dead after gather_h_fused which runs before sim_topk)
    float* pv     = xw1;                                 // N*312 used
    int*   pi     = (int*)(W2rT + (size_t)D_H * NCLS);   // N*312 used

    const int* src = ei;
    const int* dst = ei + NEDGE;

    hipMemsetAsync(cnt, 0, 10240 * sizeof(int), stream);

    transpose_count_kernel<<<(NEDGE + 255) / 256, 256, 0, stream>>>(
        W1_l, W1_r, W2_l, W2_r, W1lT, W1rT, W2lT, W2rT, dst, cnt);
    prefix_kernel<<<1, 256, 0, stream>>>(cnt, rowptr, cursor);
    bucket_kernel<<<(NEDGE + 255) / 256, 256, 0, stream>>>(src, dst, cursor, nbr);
    proj1_kernel<<<(N_NODES + 7) / 8, 256, 0, stream>>>(x, W1lT, W1rT, xw1, xwr);
    gather_h_fused_kernel<<<(N_NODES + 3) / 4, 256, 0, stream>>>(
        xw1, xwr, nbr, rowptr, cnt, b1, W2lT, W2rT, h, en, enb, out_h, hwl, hwr);
    gather_lc_kernel<<<(N_NODES + 3) / 4, 256, 0, stream>>>(hwl, hwr, nbr, rowptr, cnt, b2, lcls);
    sim_topk_kernel<<<RT * CSPL, 256, 0, stream>>>(enb, mask, pv, pi);
    rescore_merge_kernel<<<(N_NODES + 3) / 4, 256, 0, stream>>>(en, mask, pv, pi, y, lcls, out);
}

// Round 17
// 451.791 us; speedup vs baseline: 1.1588x; 1.0423x over previous
//
#include <hip/hip_runtime.h>
#include <math.h>

#define N_NODES 10000
#define D_IN    512
#define D_H     256
#define NCLS    40
#define NEDGE   160000
#define KTOP    16
#define NFRAG   625            // 10000 / 16 column fragments
#define CSPL    13             // column splits
#define ROWS    64             // rows per block (16 per wave)
#define RT      157            // ceil(10000/64) row tiles
#define SLOTS   6              // per-lane-stream top-6
#define LSTREAM 52             // lane-streams per row = CSPL * 4 lh-groups
#define CPR     (LSTREAM * SLOTS)   // candidates per row = 312
#define RESC    24             // exactly-rescored candidates per row (bf16 top-24)

typedef __attribute__((ext_vector_type(8))) short bf16x8;
typedef __attribute__((ext_vector_type(4))) float f32x4;

__device__ __forceinline__ void gload_lds16(const void* g, void* l) {
    __builtin_amdgcn_global_load_lds(
        (const __attribute__((address_space(1))) void*)g,
        (__attribute__((address_space(3))) void*)l, 16, 0, 0);
}

// ---------------- transpose weights + degree count (fused, disjoint index ranges) ----------------
__global__ void transpose_count_kernel(const float* __restrict__ W1_l, const float* __restrict__ W1_r,
                                       const float* __restrict__ W2_l, const float* __restrict__ W2_r,
                                       float* __restrict__ W1lT, float* __restrict__ W1rT,
                                       float* __restrict__ W2lT, float* __restrict__ W2rT,
                                       const int* __restrict__ dst, int* __restrict__ cnt) {
    int i = blockIdx.x * 256 + threadIdx.x;
    if (i < D_H * D_IN) {
        int r = i / D_IN, c = i % D_IN;
        W1lT[(size_t)c * D_H + r] = W1_l[i];
        W1rT[(size_t)c * D_H + r] = W1_r[i];
    }
    if (i < NCLS * D_H) {
        int r = i / D_H, c = i % D_H;
        W2lT[(size_t)c * NCLS + r] = W2_l[i];
        W2rT[(size_t)c * NCLS + r] = W2_r[i];
    }
    if (i < NEDGE) {
        int d = dst[i];
        d = (d >= 0 && d < N_NODES) ? d : 0;
        atomicAdd(&cnt[d], 1);
    }
}

// ---------------- fused: block 0 = prefix scan; blocks 1.. = proj1 ----------------
__global__ __launch_bounds__(256) void proj1_prefix_kernel(const float* __restrict__ x,
        const float* __restrict__ W1lT, const float* __restrict__ W1rT,
        float* __restrict__ xw1, float* __restrict__ xwr,
        const int* __restrict__ cnt, int* __restrict__ rowptr, int* __restrict__ cursor) {
    if (blockIdx.x == 0) {
        // ---- prefix scan -> rowptr, cursor (single block) ----
        __shared__ int sp[256];
        int t = threadIdx.x;
        int b0 = t * 40;
        int e0 = (b0 + 40 < N_NODES) ? b0 + 40 : N_NODES;
        int s = 0;
        for (int i = b0; i < e0; i++) s += cnt[i];
        sp[t] = s;
        __syncthreads();
        for (int o = 1; o < 256; o <<= 1) {
            int add = (t >= o) ? sp[t - o] : 0;
            __syncthreads();
            sp[t] += add;
            __syncthreads();
        }
        int run = sp[t] - s;     // exclusive prefix
        for (int i = b0; i < e0; i++) {
            rowptr[i] = run; cursor[i] = run; run += cnt[i];
        }
        if (t == 255) rowptr[N_NODES] = run;
        return;
    }
    // ---- proj1: xw1 = x @ W1_l^T ; xwr = x @ W1_r^T ----
    __shared__ float sx[8][D_IN];
    int tid = threadIdx.x;
    int nb0 = (blockIdx.x - 1) * 8;
    #pragma unroll
    for (int u = 0; u < 4; u++) {
        int s = tid + u * 256;          // 0..1023
        int nb = s >> 7;                // 0..7
        int c4 = (s & 127) << 2;        // 0..508
        int n = nb0 + nb;
        float4 v = make_float4(0.f, 0.f, 0.f, 0.f);
        if (n < N_NODES) v = *(const float4*)&x[(size_t)n * D_IN + c4];
        *(float4*)&sx[nb][c4] = v;
    }
    __syncthreads();
    int j = tid;
    float accl[8] = {0,0,0,0,0,0,0,0};
    float accr[8] = {0,0,0,0,0,0,0,0};
    for (int i = 0; i < D_IN; i += 4) {
        float wl0 = W1lT[(size_t)(i + 0) * D_H + j];
        float wl1 = W1lT[(size_t)(i + 1) * D_H + j];
        float wl2 = W1lT[(size_t)(i + 2) * D_H + j];
        float wl3 = W1lT[(size_t)(i + 3) * D_H + j];
        float wr0 = W1rT[(size_t)(i + 0) * D_H + j];
        float wr1 = W1rT[(size_t)(i + 1) * D_H + j];
        float wr2 = W1rT[(size_t)(i + 2) * D_H + j];
        float wr3 = W1rT[(size_t)(i + 3) * D_H + j];
        #pragma unroll
        for (int nb = 0; nb < 8; nb++) {
            float4 xx = *(const float4*)&sx[nb][i];
            float tl = accl[nb], tr = accr[nb];
            tl = fmaf(xx.x, wl0, tl); tl = fmaf(xx.y, wl1, tl);
            tl = fmaf(xx.z, wl2, tl); tl = fmaf(xx.w, wl3, tl);
            tr = fmaf(xx.x, wr0, tr); tr = fmaf(xx.y, wr1, tr);
            tr = fmaf(xx.z, wr2, tr); tr = fmaf(xx.w, wr3, tr);
            accl[nb] = tl; accr[nb] = tr;
        }
    }
    for (int nb = 0; nb < 8; nb++) {
        int n = nb0 + nb;
        if (n < N_NODES) {
            xw1[(size_t)n * D_H + j] = accl[nb];
            xwr[(size_t)n * D_H + j] = accr[nb];
        }
    }
}

// ---------------- bucket edges by dst ----------------
__global__ void bucket_kernel(const int* __restrict__ src, const int* __restrict__ dst,
                              int* __restrict__ cursor, int* __restrict__ nbr) {
    int e = blockIdx.x * 256 + threadIdx.x;
    if (e < NEDGE) {
        int d = dst[e];
        d = (d >= 0 && d < N_NODES) ? d : 0;
        int p = atomicAdd(&cursor[d], 1);
        if (p >= 0 && p < NEDGE) {
            int s = src[e];
            nbr[p] = (s >= 0 && s < N_NODES) ? s : 0;
        }
    }
}

// ---------------- fused: h = elu(mean(xw1[nbr]) + b1 + xwr); en/enb = normalize(h);
//                  out_h = h; hwl = h @ W2_l^T; hwr = h @ W2_r^T ----------------
__global__ __launch_bounds__(256) void gather_h_fused_kernel(const float* __restrict__ xw1,
        const float* __restrict__ xwr, const int* __restrict__ nbr,
        const int* __restrict__ rowptr, const int* __restrict__ cnt,
        const float* __restrict__ b1, const float* __restrict__ W2lT,
        const float* __restrict__ W2rT, float* __restrict__ h, float* __restrict__ en,
        unsigned short* __restrict__ enb, float* __restrict__ outh,
        float* __restrict__ hwl, float* __restrict__ hwr) {
    __shared__ float sh[4][D_H];
    int wid = threadIdx.x >> 6, lane = threadIdx.x & 63;
    int n = blockIdx.x * 4 + wid;
    if (n >= N_NODES) return;
    int st = rowptr[n], deg = cnt[n];
    float a[4] = {0,0,0,0};
    for (int j = 0; j < deg; j++) {
        int s = nbr[st + j];
        float4 v = *(const float4*)&xw1[(size_t)s * D_H + lane * 4];
        a[0] += v.x; a[1] += v.y; a[2] += v.z; a[3] += v.w;
    }
    float inv = 1.0f / fmaxf((float)deg, 1.0f);
    float4 r4 = *(const float4*)&xwr[(size_t)n * D_H + lane * 4];
    float4 bb = *(const float4*)&b1[lane * 4];
    float o0 = a[0] * inv + bb.x + r4.x;
    float o1 = a[1] * inv + bb.y + r4.y;
    float o2 = a[2] * inv + bb.z + r4.z;
    float o3 = a[3] * inv + bb.w + r4.w;
    o0 = o0 > 0.f ? o0 : expm1f(o0);
    o1 = o1 > 0.f ? o1 : expm1f(o1);
    o2 = o2 > 0.f ? o2 : expm1f(o2);
    o3 = o3 > 0.f ? o3 : expm1f(o3);
    float4 hv = make_float4(o0, o1, o2, o3);
    *(float4*)&h[(size_t)n * D_H + lane * 4] = hv;
    *(float4*)&outh[(size_t)n * D_H + lane * 4] = hv;
    *(float4*)&sh[wid][lane * 4] = hv;          // wave-private row; no block sync needed

    // norm -> en (fp32) + enb (bf16)
    float ss = o0 * o0 + o1 * o1 + o2 * o2 + o3 * o3;
    for (int o = 32; o; o >>= 1) ss += __shfl_xor(ss, o);
    float ninv = 1.0f / fmaxf(sqrtf(ss), 1e-8f);
    float e[4] = {o0 * ninv, o1 * ninv, o2 * ninv, o3 * ninv};
    *(float4*)&en[(size_t)n * D_H + lane * 4] = make_float4(e[0], e[1], e[2], e[3]);
    unsigned int p[4];
    #pragma unroll
    for (int k = 0; k < 4; k++) {
        unsigned int ub = __float_as_uint(e[k]);
        p[k] = (ub + 0x7FFFu + ((ub >> 16) & 1u)) >> 16;   // RNE to bf16
    }
    uint2 packed = make_uint2(p[0] | (p[1] << 16), p[2] | (p[3] << 16));
    *(uint2*)&enb[(size_t)n * D_H + lane * 4] = packed;

    // proj2: hwl/hwr for own node (lanes 0..39)
    if (lane < NCLS) {
        float al = 0.f, ar = 0.f;
        for (int i = 0; i < D_H; i++) {
            float hvv = sh[wid][i];
            al = fmaf(hvv, W2lT[(size_t)i * NCLS + lane], al);
            ar = fmaf(hvv, W2rT[(size_t)i * NCLS + lane], ar);
        }
        hwl[(size_t)n * NCLS + lane] = al;
        hwr[(size_t)n * NCLS + lane] = ar;
    }
}

// ---------------- MFMA bf16 prefilter, ring-3 LDS + counted vmcnt (R13/R15 structure) ----------------
// pv/pi stored STREAM-MAJOR ([r][stream*SLOTS+k]) -> dense 24B writes per lane.
__global__ __launch_bounds__(256) void sim_topk_kernel(const unsigned short* __restrict__ enb,
        const float* __restrict__ mask, float* __restrict__ pv, int* __restrict__ pi) {
    __shared__ __align__(16) char Abuf[3][8192];   // 3 x 8KB ring

    int rt = blockIdx.x / CSPL, cs = blockIdx.x % CSPL;
    int tid = threadIdx.x;
    int w = tid >> 6, l = tid & 63;
    int l15 = l & 15, lh = l >> 4;            // lh: 0..3
    int r = rt * ROWS + w * 16 + l15;         // this lane's sim row
    int rc = (r < N_NODES) ? r : (N_NODES - 1);

    // contiguous fragment chunk: cs=0 -> [0,49), cs>=1 -> [48cs+1, 48cs+49)
    int fbeg = cs * 48 + (cs ? 1 : 0);
    int fend = fbeg + (cs ? 48 : 49);

    // B fragments: own row of enb, full K=256
    bf16x8 bfr[8];
    const unsigned short* brow = enb + (size_t)rc * D_H + 8 * lh;
    #pragma unroll
    for (int ks = 0; ks < 8; ks++) bfr[ks] = *(const bf16x8*)(brow + ks * 32);

    float tv[SLOTS]; int ti[SLOTS];
    #pragma unroll
    for (int k = 0; k < SLOTS; k++) { tv[k] = -INFINITY; ti[k] = 0; }

    const float* mrow = mask + (size_t)rc * N_NODES;

    // swizzled ds_read byte offsets within a tile (8, per-lane constants)
    int offs[8];
    {
        int swz = (l15 & 7) << 4;
        #pragma unroll
        for (int ks = 0; ks < 8; ks++) offs[ks] = (lh * 16 + ks * 64) ^ swz;
    }

    // staging geometry: wave w covers tile bytes [w*2048, w*2048+2048) in 2 gload_lds.
    int row0 = 4 * w + (l >> 5);
    int row1 = row0 + 2;
    int tcol = l & 31;
    int g0 = tcol ^ (row0 & 7);
    int g1 = tcol ^ (row1 & 7);
    const char* gB = (const char*)enb;
    char* lds0 = &Abuf[0][0];

    // prologue: stage fbeg -> buf0, fbeg+1 -> buf1 (chunk length >= 48 so fbeg+1 < fend)
    gload_lds16(gB + (((size_t)(fbeg * 16 + row0)) << 9) + g0 * 16, lds0 + w * 2048);
    gload_lds16(gB + (((size_t)(fbeg * 16 + row1)) << 9) + g1 * 16, lds0 + w * 2048 + 1024);
    gload_lds16(gB + (((size_t)((fbeg + 1) * 16 + row0)) << 9) + g0 * 16, lds0 + 8192 + w * 2048);
    gload_lds16(gB + (((size_t)((fbeg + 1) * 16 + row1)) << 9) + g1 * 16, lds0 + 8192 + w * 2048 + 1024);

    float4 mm  = *(const float4*)&mrow[fbeg * 16 + lh * 4];
    float4 mm1 = *(const float4*)&mrow[(fbeg + 1) * 16 + lh * 4];

    int cur = 0;
    for (int f = fbeg; f < fend; ++f) {
        bool more = (f + 1 < fend);            // uniform across block
        // [A] own tile-f loads complete (counted; never 0 mid-loop)
        if (more) asm volatile("s_waitcnt vmcnt(2)" ::: "memory");
        else      asm volatile("s_waitcnt vmcnt(0)" ::: "memory");
        // [B] all waves' tile-f loads landed; all waves done reading buf[(cur+2)%3]'s old tile
        __builtin_amdgcn_s_barrier();
        __builtin_amdgcn_sched_barrier(0);
        // [C] issue tile f+2 into the freed buffer; prefetch mask f+2
        float4 mm2 = make_float4(0.f, 0.f, 0.f, 0.f);
        if (f + 2 < fend) {
            int nb = cur + 2; nb = (nb >= 3) ? nb - 3 : nb;
            char* dst2 = lds0 + nb * 8192 + w * 2048;
            gload_lds16(gB + (((size_t)((f + 2) * 16 + row0)) << 9) + g0 * 16, dst2);
            gload_lds16(gB + (((size_t)((f + 2) * 16 + row1)) << 9) + g1 * 16, dst2 + 1024);
            mm2 = *(const float4*)&mrow[(f + 2) * 16 + lh * 4];
        }
        // [D] compute on buf[cur]
        const char* lbase = lds0 + cur * 8192 + l15 * 512;
        f32x4 acc = {0.f, 0.f, 0.f, 0.f};
        #pragma unroll
        for (int ks = 0; ks < 8; ks++) {
            bf16x8 af = *(const bf16x8*)(lbase + offs[ks]);
            acc = __builtin_amdgcn_mfma_f32_16x16x32_bf16(af, bfr[ks], acc, 0, 0, 0);
        }

        int c0 = f * 16 + lh * 4;
        float vv[4];
        vv[0] = acc[0] * mm.x; vv[1] = acc[1] * mm.y;
        vv[2] = acc[2] * mm.z; vv[3] = acc[3] * mm.w;
        // branchless top-6 insert, shared compares; strict > keeps earliest col on ties
        #pragma unroll
        for (int j = 0; j < 4; j++) {
            float v = vv[j]; int c = c0 + j;
            bool hh[SLOTS];
            #pragma unroll
            for (int k = 0; k < SLOTS; k++) hh[k] = tv[k] < v;
            float nv[SLOTS]; int ni[SLOTS];
            #pragma unroll
            for (int k = 0; k < SLOTS - 1; k++) {
                nv[k] = hh[k + 1] ? tv[k + 1] : (hh[k] ? v : tv[k]);
                ni[k] = hh[k + 1] ? ti[k + 1] : (hh[k] ? c : ti[k]);
            }
            nv[SLOTS - 1] = hh[SLOTS - 1] ? v : tv[SLOTS - 1];
            ni[SLOTS - 1] = hh[SLOTS - 1] ? c : ti[SLOTS - 1];
            #pragma unroll
            for (int k = 0; k < SLOTS; k++) { tv[k] = nv[k]; ti[k] = ni[k]; }
        }

        mm = mm1; mm1 = mm2;
        cur = (cur == 2) ? 0 : cur + 1;
    }

    if (r < N_NODES) {
        int stream = cs * 4 + lh;              // 0..51 lane-stream id
        float* pvp = pv + (size_t)r * CPR + stream * SLOTS;   // stream-major, dense
        int*   pip = pi + (size_t)r * CPR + stream * SLOTS;
        #pragma unroll
        for (int k = 0; k < SLOTS; k++) { pvp[k] = tv[k]; pip[k] = ti[k]; }
    }
}

// ---------------- fused: lc gather+log_softmax, bf16 top-24 -> exact fp32 rescore ->
//                  top-16 -> label fusion -> blend ----------------
__global__ __launch_bounds__(256) void rescore_merge_lc_kernel(const float* __restrict__ en,
        const float* __restrict__ mask, const float* __restrict__ pv, const int* __restrict__ pi,
        const int* __restrict__ y, const float* __restrict__ hwl, const float* __restrict__ hwr,
        const int* __restrict__ nbr, const int* __restrict__ rowptr, const int* __restrict__ cnt,
        const float* __restrict__ b2, float* __restrict__ out) {
    __shared__ float sen[4][D_H];
    int wid = threadIdx.x >> 6, lane = threadIdx.x & 63;
    int r = blockIdx.x * 4 + wid;
    if (r >= N_NODES) return;
    *(float4*)&sen[wid][lane * 4] = *(const float4*)&en[(size_t)r * D_H + lane * 4];

    // ---- lc: v = elu(mean(hwl[nbr]) + b2 + hwr); lcv = log_softmax(v) (bit-identical to R16) ----
    float lcv;
    {
        int st = rowptr[r], deg = cnt[r];
        float a = 0.f;
        if (lane < NCLS) {
            for (int j = 0; j < deg; j++) {
                int s = nbr[st + j];
                a += hwl[(size_t)s * NCLS + lane];
            }
        }
        float inv = 1.0f / fmaxf((float)deg, 1.0f);
        float v;
        if (lane < NCLS) {
            v = a * inv + b2[lane] + hwr[(size_t)r * NCLS + lane];
            v = v > 0.f ? v : expm1f(v);
        } else {
            v = -INFINITY;
        }
        float m = v;
        for (int o = 32; o; o >>= 1) m = fmaxf(m, __shfl_xor(m, o));
        float ex = (lane < NCLS) ? expf(v - m) : 0.0f;
        float s = ex;
        for (int o = 32; o; o >>= 1) s += __shfl_xor(s, o);
        lcv = v - m - logf(s);
    }

    // ---- Phase A: lanes 0..51 own stream `lane` (6 ascending slots, dense); pick row top-24 ----
    float v0 = -INFINITY, v1 = -INFINITY, v2 = -INFINITY;
    float v3 = -INFINITY, v4 = -INFINITY, v5 = -INFINITY;
    int   i0 = 0x7FFFFFFF, i1 = 0x7FFFFFFF, i2 = 0x7FFFFFFF;
    int   i3 = 0x7FFFFFFF, i4 = 0x7FFFFFFF, i5 = 0x7FFFFFFF;
    if (lane < LSTREAM) {
        const float* pvr = pv + (size_t)r * CPR + lane * SLOTS;
        const int*   pir = pi + (size_t)r * CPR + lane * SLOTS;
        v0 = pvr[0]; v1 = pvr[1]; v2 = pvr[2];
        v3 = pvr[3]; v4 = pvr[4]; v5 = pvr[5];
        i0 = pir[0]; i1 = pir[1]; i2 = pir[2];
        i3 = pir[3]; i4 = pir[4]; i5 = pir[5];
    }
    int p = SLOTS - 1;              // pointer to current lane max (slots ascending)
    int my_cand = 0;
    #pragma unroll 1
    for (int t = 0; t < RESC; t++) {
        float cur  = (p < 0) ? -INFINITY :
                     (p == 5 ? v5 : p == 4 ? v4 : p == 3 ? v3 : p == 2 ? v2 : p == 1 ? v1 : v0);
        int   curi = (p < 0) ? 0x7FFFFFFF :
                     (p == 5 ? i5 : p == 4 ? i4 : p == 3 ? i3 : p == 2 ? i2 : p == 1 ? i1 : i0);
        float rv = cur; int ri = curi;
        #pragma unroll
        for (int o = 1; o < 64; o <<= 1) {
            float ov = __shfl_xor(rv, o); int oi = __shfl_xor(ri, o);
            bool bet = (ov > rv) || (ov == rv && oi < ri);
            rv = bet ? ov : rv; ri = bet ? oi : ri;
        }
        if (curi == ri && p >= 0) p--;      // indices unique per row -> only winner decrements
        if (lane == t) my_cand = ri;
    }
    // broadcast: lane L and L+32 rescore candidate sel[L&31] (valid for (L&31) < RESC)
    int cand = __shfl(my_cand, lane & 31);
    cand = (cand >= 0 && cand < N_NODES) ? cand : 0;

    __syncthreads();   // sen ready

    // ---- Phase B: exact fp32 dot, 2 lanes per candidate (k-halves) ----
    int half = lane >> 5;               // 0 or 1
    const float* erow = &en[(size_t)cand * D_H + half * 128];
    const float* srow = &sen[wid][half * 128];
    float dot = 0.0f;
    #pragma unroll 8
    for (int k = 0; k < 128; k += 4) {
        float4 e = *(const float4*)&erow[k];
        dot = fmaf(srow[k + 0], e.x, dot);
        dot = fmaf(srow[k + 1], e.y, dot);
        dot = fmaf(srow[k + 2], e.z, dot);
        dot = fmaf(srow[k + 3], e.w, dot);
    }
    dot += __shfl_xor(dot, 32);
    float cv = (lane < RESC) ? dot * mask[(size_t)r * N_NODES + cand] : -INFINITY;

    // ---- Phase C: exact top-16 -> label fusion -> log-softmax -> blend ----
    float fc = 0.0f;
    #pragma unroll 1
    for (int t = 0; t < KTOP; t++) {
        float rv = cv; int ri = (lane < RESC) ? cand : 0x7FFFFFFF;
        #pragma unroll
        for (int o = 1; o < 64; o <<= 1) {
            float ov = __shfl_xor(rv, o); int oi = __shfl_xor(ri, o);
            bool bet = (ov > rv) || (ov == rv && oi < ri);
            rv = bet ? ov : rv; ri = bet ? oi : ri;
        }
        if (lane < RESC && cand == ri) cv = -INFINITY;
        int ris = (ri >= 0 && ri < N_NODES) ? ri : 0;
        int lbl = y[ris];
        if (lane == lbl) fc += expf(rv);
    }
    float fval = (lane < NCLS) ? fc : -INFINITY;
    float m = fval;
    for (int o = 32; o; o >>= 1) m = fmaxf(m, __shfl_xor(m, o));
    float ex = (lane < NCLS) ? expf(fval - m) : 0.0f;
    float s = ex;
    for (int o = 32; o; o >>= 1) s += __shfl_xor(s, o);
    if (lane < NCLS)
        out[(size_t)r * NCLS + lane] = 0.5f * lcv + 0.5f * (fval - m - logf(s));
}

extern "C" void kernel_launch(void* const* d_in, const int* in_sizes, int n_in,
                              void* d_out, int out_size, void* d_ws, size_t ws_size,
                              hipStream_t stream) {
    const float* x    = (const float*)d_in[0];
    const int*   ei   = (const int*)  d_in[1];
    const int*   y    = (const int*)  d_in[2];
    const float* mask = (const float*)d_in[3];
    const float* W1_l = (const float*)d_in[4];
    const float* b1   = (const float*)d_in[5];
    const float* W1_r = (const float*)d_in[6];
    const float* W2_l = (const float*)d_in[7];
    const float* b2   = (const float*)d_in[8];
    const float* W2_r = (const float*)d_in[9];

    float* out   = (float*)d_out;
    float* out_h = out + (size_t)N_NODES * NCLS;

    int*   cnt    = (int*)d_ws;                       // 10240
    int*   rowptr = cnt + 10240;                      // 10304
    int*   cursor = rowptr + 10304;                   // 10240
    int*   nbr    = cursor + 10240;                   // 160256
    float* xw1    = (float*)(nbr + 160256);           // N*256
    float* xwr    = xw1 + (size_t)N_NODES * D_H;      // N*256
    float* h      = xwr + (size_t)N_NODES * D_H;      // N*256
    float* en     = h   + (size_t)N_NODES * D_H;      // N*256
    unsigned short* enb = (unsigned short*)(en + (size_t)N_NODES * D_H);  // N*256 bf16
    float* lcls   = (float*)(enb + (size_t)N_NODES * D_H);                // (unused, kept for layout)
    float* hwl    = lcls + (size_t)N_NODES * NCLS;    // N*40
    float* hwr    = hwl + (size_t)N_NODES * NCLS;     // N*40
    float* W1lT   = hwr + (size_t)N_NODES * NCLS;
    float* W1rT   = W1lT + (size_t)D_IN * D_H;
    float* W2lT   = W1rT + (size_t)D_IN * D_H;
    float* W2rT   = W2lT + (size_t)D_H * NCLS;
    // pv aliases xw1+xwr (N*512 floats, dead after gather_h_fused which runs before sim_topk)
    float* pv     = xw1;                                 // N*312 used
    int*   pi     = (int*)(W2rT + (size_t)D_H * NCLS);   // N*312 used

    const int* src = ei;
    const int* dst = ei + NEDGE;

    hipMemsetAsync(cnt, 0, 10240 * sizeof(int), stream);

    transpose_count_kernel<<<(NEDGE + 255) / 256, 256, 0, stream>>>(
        W1_l, W1_r, W2_l, W2_r, W1lT, W1rT, W2lT, W2rT, dst, cnt);
    proj1_prefix_kernel<<<(N_NODES + 7) / 8 + 1, 256, 0, stream>>>(
        x, W1lT, W1rT, xw1, xwr, cnt, rowptr, cursor);
    bucket_kernel<<<(NEDGE + 255) / 256, 256, 0, stream>>>(src, dst, cursor, nbr);
    gather_h_fused_kernel<<<(N_NODES + 3) / 4, 256, 0, stream>>>(
        xw1, xwr, nbr, rowptr, cnt, b1, W2lT, W2rT, h, en, enb, out_h, hwl, hwr);
    sim_topk_kernel<<<RT * CSPL, 256, 0, stream>>>(enb, mask, pv, pi);
    rescore_merge_lc_kernel<<<(N_NODES + 3) / 4, 256, 0, stream>>>(
        en, mask, pv, pi, y, hwl, hwr, nbr, rowptr, cnt, b2, out);
}